// Round 2
// baseline (3220.860 us; speedup 1.0000x reference)
//
#include <hip/hip_runtime.h>
#include <hip/hip_bf16.h>
#include <cstdint>

#define B_IMG 512
#define NMEM  32768
#define DD    4096
#define HID   16

// ---------------- squared row norms ----------------
__global__ __launch_bounds__(256) void sqnorm_kernel(const float* __restrict__ x,
                                                     float* __restrict__ out) {
  const int row = blockIdx.x;
  const float4* p = reinterpret_cast<const float4*>(x + (size_t)row * DD);
  float s = 0.f;
#pragma unroll
  for (int j = 0; j < 4; ++j) {
    float4 v = p[threadIdx.x + 256 * j];
    s += v.x * v.x + v.y * v.y + v.z * v.z + v.w * v.w;
  }
#pragma unroll
  for (int o = 32; o > 0; o >>= 1) s += __shfl_down(s, o);
  __shared__ float ls[4];
  if ((threadIdx.x & 63) == 0) ls[threadIdx.x >> 6] = s;
  __syncthreads();
  if (threadIdx.x == 0) out[row] = (ls[0] + ls[1]) + (ls[2] + ls[3]);
}

// ---------------- distance GEMM + fused argmin ----------------
// dists[m][n] = a2[m] + b2[n] - 2 * dot(A[m], B[n]); track argmin per m.
__global__ __launch_bounds__(256) void dist_argmin_kernel(
    const float* __restrict__ A, const float* __restrict__ Bm,
    const float* __restrict__ a2, const float* __restrict__ b2,
    unsigned long long* __restrict__ best) {
  __shared__ float As[32][128];
  __shared__ float Bs[32][128];
  const int tid = threadIdx.x;
  const int m0 = blockIdx.y * 128;
  const int n0 = blockIdx.x * 128;
  const int tm = tid >> 4, tn = tid & 15;
  const int sr = tid >> 3;        // 0..31
  const int sc = (tid & 7) << 2;  // 0,4,...,28

  float acc[8][8];
#pragma unroll
  for (int i = 0; i < 8; ++i)
#pragma unroll
    for (int j = 0; j < 8; ++j) acc[i][j] = 0.f;

  for (int k0 = 0; k0 < DD; k0 += 32) {
    __syncthreads();
#pragma unroll
    for (int r = 0; r < 4; ++r) {
      const int row = sr + (r << 5);
      float4 va = *reinterpret_cast<const float4*>(&A[(size_t)(m0 + row) * DD + k0 + sc]);
      As[sc + 0][row] = va.x; As[sc + 1][row] = va.y;
      As[sc + 2][row] = va.z; As[sc + 3][row] = va.w;
      float4 vb = *reinterpret_cast<const float4*>(&Bm[(size_t)(n0 + row) * DD + k0 + sc]);
      Bs[sc + 0][row] = vb.x; Bs[sc + 1][row] = vb.y;
      Bs[sc + 2][row] = vb.z; Bs[sc + 3][row] = vb.w;
    }
    __syncthreads();
#pragma unroll 8
    for (int kk = 0; kk < 32; ++kk) {
      float4 a0 = *reinterpret_cast<const float4*>(&As[kk][tm * 8]);
      float4 a1 = *reinterpret_cast<const float4*>(&As[kk][tm * 8 + 4]);
      float4 b0 = *reinterpret_cast<const float4*>(&Bs[kk][tn * 8]);
      float4 b1 = *reinterpret_cast<const float4*>(&Bs[kk][tn * 8 + 4]);
      float a[8] = {a0.x, a0.y, a0.z, a0.w, a1.x, a1.y, a1.z, a1.w};
      float b[8] = {b0.x, b0.y, b0.z, b0.w, b1.x, b1.y, b1.z, b1.w};
#pragma unroll
      for (int i = 0; i < 8; ++i)
#pragma unroll
        for (int j = 0; j < 8; ++j) acc[i][j] += a[i] * b[j];
    }
  }

  __syncthreads();
  unsigned long long* red = reinterpret_cast<unsigned long long*>(&As[0][0]);  // [128][16]
#pragma unroll
  for (int i = 0; i < 8; ++i) {
    const int m = m0 + tm * 8 + i;
    const float a2v = a2[m];
    float bd = 3.4e38f;
    int bn = 0;
#pragma unroll
    for (int j = 0; j < 8; ++j) {
      const int n = n0 + tn * 8 + j;
      const float dval = (a2v + b2[n]) - 2.0f * acc[i][j];
      if (dval < bd) { bd = dval; bn = n; }
    }
    red[(tm * 8 + i) * 16 + tn] =
        ((unsigned long long)__float_as_uint(bd) << 32) | (unsigned)bn;
  }
  __syncthreads();
  if (tid < 128) {
    unsigned long long k = red[tid * 16];
#pragma unroll
    for (int t2 = 1; t2 < 16; ++t2) {
      unsigned long long c = red[tid * 16 + t2];
      if (c < k) k = c;
    }
    atomicMin(&best[m0 + tid], k);
  }
}

// ---------------- gather selected memory rows ----------------
__global__ __launch_bounds__(256) void gather_kernel(
    const float* __restrict__ bank, const unsigned long long* __restrict__ best,
    float* __restrict__ out) {
  const int b = blockIdx.x;
  const unsigned idx = (unsigned)(best[b] & 0xffffffffull);
  const float4* src = reinterpret_cast<const float4*>(bank + (size_t)idx * DD);
  float4* dst = reinterpret_cast<float4*>(out + (size_t)b * DD);
#pragma unroll
  for (int j = 0; j < 4; ++j)
    dst[threadIdx.x + 256 * j] = src[threadIdx.x + 256 * j];
}

// ---------------- conv layer 1: (1 or 3) -> 16, relu ----------------
__global__ __launch_bounds__(256) void conv_first_kernel(
    const float* __restrict__ p0, const float* __restrict__ p1,
    const float* __restrict__ p2, int ncin,
    const float* __restrict__ w, const float* __restrict__ bias,
    float* __restrict__ out) {
  __shared__ float sIn[3][18][18];
  __shared__ float sW[3][3][3][16];
  __shared__ float sB[16];
  const int tid = threadIdx.x;
  const int img = blockIdx.x >> 4;
  const int t = blockIdx.x & 15;
  const int y0 = (t >> 2) * 16, x0 = (t & 3) * 16;
  for (int i = tid; i < ncin * 144; i += 256) {
    int co = i & 15, r = i >> 4;  // r = ci*9 + k
    int ci = r / 9, kk = r % 9;
    sW[ci][kk / 3][kk % 3][co] = w[(co * ncin + ci) * 9 + kk];
  }
  if (tid < 16) sB[tid] = bias[tid];
  const float* ps[3] = {p0, p1, p2};
  for (int i = tid; i < ncin * 18 * 18; i += 256) {
    int x = i % 18, rest = i / 18, yy = rest % 18, ci = rest / 18;
    int gx = x0 + x - 1, gy = y0 + yy - 1;
    float v = 0.f;
    if (gx >= 0 && gx < 64 && gy >= 0 && gy < 64)
      v = ps[ci][(size_t)img * DD + gy * 64 + gx];
    sIn[ci][yy][x] = v;
  }
  __syncthreads();
  const int ly = tid >> 4, lx = tid & 15;
  float acc[16];
#pragma unroll
  for (int co = 0; co < 16; ++co) acc[co] = sB[co];
  for (int ci = 0; ci < ncin; ++ci)
#pragma unroll
    for (int ky = 0; ky < 3; ++ky)
#pragma unroll
      for (int kx = 0; kx < 3; ++kx) {
        const float v = sIn[ci][ly + ky][lx + kx];
        const float4* wp = reinterpret_cast<const float4*>(&sW[ci][ky][kx][0]);
#pragma unroll
        for (int q = 0; q < 4; ++q) {
          float4 wq = wp[q];
          acc[q * 4 + 0] += wq.x * v; acc[q * 4 + 1] += wq.y * v;
          acc[q * 4 + 2] += wq.z * v; acc[q * 4 + 3] += wq.w * v;
        }
      }
  const int px = (y0 + ly) * 64 + (x0 + lx);
  float* ob = out + (size_t)img * HID * DD + px;
#pragma unroll
  for (int co = 0; co < 16; ++co) ob[co * DD] = fmaxf(acc[co], 0.f);
}

// ---------------- conv layer 2: 16 -> 16, relu ----------------
__global__ __launch_bounds__(256) void conv_mid_kernel(
    const float* __restrict__ in, const float* __restrict__ w,
    const float* __restrict__ bias, float* __restrict__ out) {
  __shared__ float sIn[16][18][34];
  __shared__ float sW[16][3][3][16];
  __shared__ float sB[16];
  const int tid = threadIdx.x;
  const int img = blockIdx.x >> 3;
  const int t = blockIdx.x & 7;
  const int y0 = (t >> 1) * 16, x0 = (t & 1) * 32;
  for (int i = tid; i < 2304; i += 256) {
    int co = i & 15, r = i >> 4;
    int ci = r / 9, kk = r % 9;
    sW[ci][kk / 3][kk % 3][co] = w[(co * 16 + ci) * 9 + kk];
  }
  if (tid < 16) sB[tid] = bias[tid];
  const float* ib = in + (size_t)img * HID * DD;
  for (int i = tid; i < 16 * 18 * 34; i += 256) {
    int x = i % 34, rest = i / 34, yy = rest % 18, ci = rest / 18;
    int gx = x0 + x - 1, gy = y0 + yy - 1;
    float v = 0.f;
    if (gx >= 0 && gx < 64 && gy >= 0 && gy < 64) v = ib[ci * DD + gy * 64 + gx];
    sIn[ci][yy][x] = v;
  }
  __syncthreads();
  const int ly = tid >> 4;        // 0..15
  const int lx = (tid & 15) * 2;  // 0..30
  float acc0[16], acc1[16];
#pragma unroll
  for (int co = 0; co < 16; ++co) { acc0[co] = sB[co]; acc1[co] = sB[co]; }
#pragma unroll 2
  for (int ci = 0; ci < 16; ++ci)
#pragma unroll
    for (int ky = 0; ky < 3; ++ky)
#pragma unroll
      for (int kx = 0; kx < 3; ++kx) {
        const float v0 = sIn[ci][ly + ky][lx + kx];
        const float v1 = sIn[ci][ly + ky][lx + kx + 1];
        const float4* wp = reinterpret_cast<const float4*>(&sW[ci][ky][kx][0]);
#pragma unroll
        for (int q = 0; q < 4; ++q) {
          float4 wq = wp[q];
          acc0[q * 4 + 0] += wq.x * v0; acc1[q * 4 + 0] += wq.x * v1;
          acc0[q * 4 + 1] += wq.y * v0; acc1[q * 4 + 1] += wq.y * v1;
          acc0[q * 4 + 2] += wq.z * v0; acc1[q * 4 + 2] += wq.z * v1;
          acc0[q * 4 + 3] += wq.w * v0; acc1[q * 4 + 3] += wq.w * v1;
        }
      }
  const int px = (y0 + ly) * 64 + (x0 + lx);
  float* ob = out + (size_t)img * HID * DD + px;
#pragma unroll
  for (int co = 0; co < 16; ++co) {
    ob[co * DD] = fmaxf(acc0[co], 0.f);
    ob[co * DD + 1] = fmaxf(acc1[co], 0.f);
  }
}

// ---------------- conv layer 3: 16 -> 1, +epilogue ----------------
// mode 0: out = addend - conv   (base_out = noisy - conv3)
// mode 1: out = addend + conv   (final   = base_out + delta)
__global__ __launch_bounds__(256) void conv_last_kernel(
    const float* __restrict__ in, const float* __restrict__ w,
    const float* __restrict__ bias, const float* __restrict__ addend,
    int mode, float* __restrict__ outp) {
  __shared__ float sIn[16][18][18];
  __shared__ float sW[16][9];
  const int tid = threadIdx.x;
  const int img = blockIdx.x >> 4;
  const int t = blockIdx.x & 15;
  const int y0 = (t >> 2) * 16, x0 = (t & 3) * 16;
  for (int i = tid; i < 144; i += 256) sW[i / 9][i % 9] = w[i];
  for (int i = tid; i < 16 * 18 * 18; i += 256) {
    int x = i % 18, rest = i / 18, yy = rest % 18, ci = rest / 18;
    int gx = x0 + x - 1, gy = y0 + yy - 1;
    float v = 0.f;
    if (gx >= 0 && gx < 64 && gy >= 0 && gy < 64)
      v = in[(size_t)img * HID * DD + ci * DD + gy * 64 + gx];
    sIn[ci][yy][x] = v;
  }
  __syncthreads();
  const int ly = tid >> 4, lx = tid & 15;
  float acc = bias[0];
#pragma unroll
  for (int ci = 0; ci < 16; ++ci)
#pragma unroll
    for (int ky = 0; ky < 3; ++ky)
#pragma unroll
      for (int kx = 0; kx < 3; ++kx)
        acc += sW[ci][ky * 3 + kx] * sIn[ci][ly + ky][lx + kx];
  const int px = (y0 + ly) * 64 + (x0 + lx);
  const float ad = addend[(size_t)img * DD + px];
  outp[(size_t)img * DD + px] = (mode == 0) ? (ad - acc) : (ad + acc);
}

extern "C" void kernel_launch(void* const* d_in, const int* in_sizes, int n_in,
                              void* d_out, int out_size, void* d_ws, size_t ws_size,
                              hipStream_t stream) {
  (void)in_sizes; (void)n_in; (void)out_size;
  const float* noisy = (const float*)d_in[0];
  const float* memN  = (const float*)d_in[1];
  const float* memC  = (const float*)d_in[2];
  const float* bw1 = (const float*)d_in[3];
  const float* bb1 = (const float*)d_in[4];
  const float* bw2 = (const float*)d_in[5];
  const float* bb2 = (const float*)d_in[6];
  const float* bw3 = (const float*)d_in[7];
  const float* bb3 = (const float*)d_in[8];
  const float* aw1 = (const float*)d_in[9];
  const float* ab1 = (const float*)d_in[10];
  const float* aw2 = (const float*)d_in[11];
  const float* ab2 = (const float*)d_in[12];
  const float* aw3 = (const float*)d_in[13];
  const float* ab3 = (const float*)d_in[14];
  float* out_f32 = (float*)d_out;   // reference output dtype is float32

  char* ws = (char*)d_ws;
  size_t off = 0;
  auto take = [&](size_t bytes) -> char* {
    char* p = ws + off;
    off += (bytes + 255) & ~(size_t)255;
    return p;
  };
  float* b2 = (float*)take((size_t)NMEM * 4);
  float* a2 = (float*)take((size_t)B_IMG * 4);
  unsigned long long* best = (unsigned long long*)take((size_t)B_IMG * 8);
  float* base_out = (float*)take((size_t)B_IMG * DD * 4);
  float* mem_sel  = (float*)take((size_t)B_IMG * DD * 4);
  int CB = 128;  // batch chunk for conv intermediates
  while (CB > 1 && off + 2ull * CB * HID * DD * 4 + 512 > ws_size) CB >>= 1;
  float* h1 = (float*)take((size_t)CB * HID * DD * 4);
  float* h2 = (float*)take((size_t)CB * HID * DD * 4);

  // 1) norms
  sqnorm_kernel<<<NMEM, 256, 0, stream>>>(memN, b2);
  sqnorm_kernel<<<B_IMG, 256, 0, stream>>>(noisy, a2);
  // 2) argmin over distances
  hipMemsetAsync(best, 0xFF, (size_t)B_IMG * 8, stream);
  dist_argmin_kernel<<<dim3(NMEM / 128, B_IMG / 128), 256, 0, stream>>>(
      noisy, memN, a2, b2, best);
  // 3) gather selected clean memories
  gather_kernel<<<B_IMG, 256, 0, stream>>>(memC, best, mem_sel);

  // 4) conv pipeline, chunked over batch
  for (int c0 = 0; c0 < B_IMG; c0 += CB) {
    const float* np_ = noisy + (size_t)c0 * DD;
    float* bo = base_out + (size_t)c0 * DD;
    const float* ms = mem_sel + (size_t)c0 * DD;
    // base denoiser
    conv_first_kernel<<<CB * 16, 256, 0, stream>>>(np_, nullptr, nullptr, 1, bw1, bb1, h1);
    conv_mid_kernel<<<CB * 8, 256, 0, stream>>>(h1, bw2, bb2, h2);
    conv_last_kernel<<<CB * 16, 256, 0, stream>>>(h2, bw3, bb3, np_, 0, bo);
    // adapter (input = concat[noisy, base_out, mem_clean])
    conv_first_kernel<<<CB * 16, 256, 0, stream>>>(np_, bo, ms, 3, aw1, ab1, h1);
    conv_mid_kernel<<<CB * 8, 256, 0, stream>>>(h1, aw2, ab2, h2);
    conv_last_kernel<<<CB * 16, 256, 0, stream>>>(
        h2, aw3, ab3, bo, 1, out_f32 + (size_t)c0 * DD);
  }
}

// Round 3
// 1501.561 us; speedup vs baseline: 2.1450x; 2.1450x over previous
//
#include <hip/hip_runtime.h>
#include <hip/hip_bf16.h>
#include <cstdint>

#define B_IMG 512
#define NMEM  32768
#define DD    4096
#define HID   16

typedef __attribute__((ext_vector_type(8))) short short8;
typedef __attribute__((ext_vector_type(4))) float f32x4;
typedef unsigned long long ull;

__device__ __forceinline__ void gload16(const void* g, const void* l) {
  __builtin_amdgcn_global_load_lds(
      (const __attribute__((address_space(1))) void*)g,
      (__attribute__((address_space(3))) void*)l, 16, 0, 0);
}

// ---------------- squared row norms (fallback path) ----------------
__global__ __launch_bounds__(256) void sqnorm_kernel(const float* __restrict__ x,
                                                     float* __restrict__ out) {
  const int row = blockIdx.x;
  const float4* p = reinterpret_cast<const float4*>(x + (size_t)row * DD);
  float s = 0.f;
#pragma unroll
  for (int j = 0; j < 4; ++j) {
    float4 v = p[threadIdx.x + 256 * j];
    s += v.x * v.x + v.y * v.y + v.z * v.z + v.w * v.w;
  }
#pragma unroll
  for (int o = 32; o > 0; o >>= 1) s += __shfl_down(s, o);
  __shared__ float ls[4];
  if ((threadIdx.x & 63) == 0) ls[threadIdx.x >> 6] = s;
  __syncthreads();
  if (threadIdx.x == 0) out[row] = (ls[0] + ls[1]) + (ls[2] + ls[3]);
}

// ---------------- split f32 -> bf16 hi/lo + row sqnorm ----------------
__global__ __launch_bounds__(256) void split_kernel(const float* __restrict__ x,
                                                    ushort* __restrict__ hi,
                                                    ushort* __restrict__ lo,
                                                    float* __restrict__ nrm) {
  const int row = blockIdx.x;
  const int t = threadIdx.x;
  const float4* p = reinterpret_cast<const float4*>(x + (size_t)row * DD);
  ushort4* ph = reinterpret_cast<ushort4*>(hi + (size_t)row * DD);
  ushort4* pl = reinterpret_cast<ushort4*>(lo + (size_t)row * DD);
  float s = 0.f;
#pragma unroll
  for (int j = 0; j < 4; ++j) {
    float4 v = p[t + 256 * j];
    float vv[4] = {v.x, v.y, v.z, v.w};
    ushort4 h, l;
    ushort* hp = &h.x;
    ushort* lp = &l.x;
#pragma unroll
    for (int q = 0; q < 4; ++q) {
      float f = vv[q];
      s += f * f;
      uint32_t u = __float_as_uint(f);
      uint32_t hb = (u + 0x7fffu + ((u >> 16) & 1u)) >> 16;  // RNE to bf16
      hp[q] = (ushort)hb;
      float fh = __uint_as_float(hb << 16);
      float fl = f - fh;  // exact
      uint32_t u2 = __float_as_uint(fl);
      lp[q] = (ushort)((u2 + 0x7fffu + ((u2 >> 16) & 1u)) >> 16);
    }
    ph[t + 256 * j] = h;
    pl[t + 256 * j] = l;
  }
#pragma unroll
  for (int o = 32; o > 0; o >>= 1) s += __shfl_down(s, o);
  __shared__ float ls[4];
  if ((t & 63) == 0) ls[t >> 6] = s;
  __syncthreads();
  if (t == 0) nrm[row] = (ls[0] + ls[1]) + (ls[2] + ls[3]);
}

// ---------------- split-bf16 MFMA distance GEMM + fused argmin ----------------
// acc = Ahi.Bhi + Ahi.Blo + Alo.Bhi ; dist = a2[m]+b2[n]-2*acc ; argmin per m.
__global__ __launch_bounds__(256) void dist_mfma_kernel(
    const ushort* __restrict__ Ah_g, const ushort* __restrict__ Al_g,
    const ushort* __restrict__ Bh_g, const ushort* __restrict__ Bl_g,
    const float* __restrict__ a2, const float* __restrict__ b2,
    ull* __restrict__ best) {
  // grid remap: 4 m-blocks of the same n-panel sit 8 dispatch-ids apart -> same XCD L2
  const int d = blockIdx.x;
  const int xcd = d & 7;
  const int rest = d >> 3;
  const int mb = rest & 3;
  const int nb = (rest >> 2) * 8 + xcd;
  const int m0 = mb * 128;
  const int n0 = nb * 128;

  __shared__ short8 ldsbuf[2048];  // 32 KB: Ah | Al | Bh | Bl, each 128x32 bf16
  char* lb = (char*)ldsbuf;

  const int t = threadIdx.x;
  const int lane = t & 63;
  const int wid = t >> 6;
  const int wm = wid >> 1;  // 0..1
  const int wn = wid & 1;   // 0..1

  f32x4 acc[4][4];
#pragma unroll
  for (int mi = 0; mi < 4; ++mi)
#pragma unroll
    for (int ni = 0; ni < 4; ++ni) {
      f32x4 z = {0.f, 0.f, 0.f, 0.f};
      acc[mi][ni] = z;
    }

  const ushort* gptrs[4] = {Ah_g, Al_g, Bh_g, Bl_g};
  const int rbase[4] = {m0, m0, n0, n0};

  for (int k0 = 0; k0 < DD; k0 += 32) {
    // ---- stage 4 tiles (linear LDS dest; XOR-swizzled global source) ----
#pragma unroll
    for (int x = 0; x < 4; ++x) {
      const ushort* P = gptrs[x];
#pragma unroll
      for (int j = 0; j < 2; ++j) {
        const int e = (j * 256 + t) * 8;       // bf16 index in tile
        const int row = e >> 5;                // 0..127
        const int gpos = (e >> 3) & 3;         // 16B granule in row
        const int col = ((gpos ^ ((row >> 1) & 3)) << 3);
        gload16(P + ((size_t)(rbase[x] + row) * DD + k0 + col),
                lb + x * 8192 + e * 2);
      }
    }
    __syncthreads();  // vmcnt drain + all waves

    // ---- fragments + MFMA ----
    short8 ah[4], al[4];
#pragma unroll
    for (int mi = 0; mi < 4; ++mi) {
      const int r = wm * 64 + mi * 16 + (lane & 15);
      const int off = r * 64 + ((((lane >> 4) ^ (r >> 1)) & 3) << 4);
      ah[mi] = *(const short8*)(lb + off);
      al[mi] = *(const short8*)(lb + 8192 + off);
    }
#pragma unroll
    for (int ni = 0; ni < 4; ++ni) {
      const int r = wn * 64 + ni * 16 + (lane & 15);
      const int off = r * 64 + ((((lane >> 4) ^ (r >> 1)) & 3) << 4);
      short8 bh = *(const short8*)(lb + 16384 + off);
      short8 bl = *(const short8*)(lb + 24576 + off);
#pragma unroll
      for (int mi = 0; mi < 4; ++mi) {
        acc[mi][ni] = __builtin_amdgcn_mfma_f32_16x16x32_bf16(ah[mi], bh, acc[mi][ni], 0, 0, 0);
        acc[mi][ni] = __builtin_amdgcn_mfma_f32_16x16x32_bf16(ah[mi], bl, acc[mi][ni], 0, 0, 0);
        acc[mi][ni] = __builtin_amdgcn_mfma_f32_16x16x32_bf16(al[mi], bh, acc[mi][ni], 0, 0, 0);
      }
    }
    __syncthreads();  // compute done before next stage overwrites
  }

  // ---- epilogue: dist + per-row argmin, one atomic per row per block ----
#pragma unroll
  for (int mi = 0; mi < 4; ++mi)
#pragma unroll
    for (int j = 0; j < 4; ++j) {
      const int m = m0 + wm * 64 + mi * 16 + (lane >> 4) * 4 + j;
      const float a2v = a2[m];
      float bd = 3.4e38f;
      int bn = 0;
#pragma unroll
      for (int ni = 0; ni < 4; ++ni) {
        const int n = n0 + wn * 64 + ni * 16 + (lane & 15);
        const float dv = (a2v + b2[n]) - 2.0f * acc[mi][ni][j];
        if (dv < bd) { bd = dv; bn = n; }
      }
      ull key = ((ull)__float_as_uint(bd) << 32) | (unsigned)bn;
#pragma unroll
      for (int msk = 1; msk < 16; msk <<= 1) {
        ull o = __shfl_xor(key, msk);
        if (o < key) key = o;
      }
      if ((lane & 15) == 0) atomicMin(&best[m], key);
    }
}

// ---------------- fp32 fallback distance GEMM + argmin ----------------
__global__ __launch_bounds__(256) void dist_argmin_kernel(
    const float* __restrict__ A, const float* __restrict__ Bm,
    const float* __restrict__ a2, const float* __restrict__ b2,
    ull* __restrict__ best) {
  __shared__ float As[32][128];
  __shared__ float Bs[32][128];
  const int tid = threadIdx.x;
  const int m0 = blockIdx.y * 128;
  const int n0 = blockIdx.x * 128;
  const int tm = tid >> 4, tn = tid & 15;
  const int sr = tid >> 3;
  const int sc = (tid & 7) << 2;
  float acc[8][8];
#pragma unroll
  for (int i = 0; i < 8; ++i)
#pragma unroll
    for (int j = 0; j < 8; ++j) acc[i][j] = 0.f;
  for (int k0 = 0; k0 < DD; k0 += 32) {
    __syncthreads();
#pragma unroll
    for (int r = 0; r < 4; ++r) {
      const int row = sr + (r << 5);
      float4 va = *reinterpret_cast<const float4*>(&A[(size_t)(m0 + row) * DD + k0 + sc]);
      As[sc + 0][row] = va.x; As[sc + 1][row] = va.y;
      As[sc + 2][row] = va.z; As[sc + 3][row] = va.w;
      float4 vb = *reinterpret_cast<const float4*>(&Bm[(size_t)(n0 + row) * DD + k0 + sc]);
      Bs[sc + 0][row] = vb.x; Bs[sc + 1][row] = vb.y;
      Bs[sc + 2][row] = vb.z; Bs[sc + 3][row] = vb.w;
    }
    __syncthreads();
#pragma unroll 8
    for (int kk = 0; kk < 32; ++kk) {
      float4 a0 = *reinterpret_cast<const float4*>(&As[kk][tm * 8]);
      float4 a1 = *reinterpret_cast<const float4*>(&As[kk][tm * 8 + 4]);
      float4 b0 = *reinterpret_cast<const float4*>(&Bs[kk][tn * 8]);
      float4 b1 = *reinterpret_cast<const float4*>(&Bs[kk][tn * 8 + 4]);
      float a[8] = {a0.x, a0.y, a0.z, a0.w, a1.x, a1.y, a1.z, a1.w};
      float b[8] = {b0.x, b0.y, b0.z, b0.w, b1.x, b1.y, b1.z, b1.w};
#pragma unroll
      for (int i = 0; i < 8; ++i)
#pragma unroll
        for (int j = 0; j < 8; ++j) acc[i][j] += a[i] * b[j];
    }
  }
  __syncthreads();
  ull* red = reinterpret_cast<ull*>(&As[0][0]);
#pragma unroll
  for (int i = 0; i < 8; ++i) {
    const int m = m0 + tm * 8 + i;
    const float a2v = a2[m];
    float bd = 3.4e38f;
    int bn = 0;
#pragma unroll
    for (int j = 0; j < 8; ++j) {
      const int n = n0 + tn * 8 + j;
      const float dval = (a2v + b2[n]) - 2.0f * acc[i][j];
      if (dval < bd) { bd = dval; bn = n; }
    }
    red[(tm * 8 + i) * 16 + tn] = ((ull)__float_as_uint(bd) << 32) | (unsigned)bn;
  }
  __syncthreads();
  if (tid < 128) {
    ull k = red[tid * 16];
#pragma unroll
    for (int t2 = 1; t2 < 16; ++t2) {
      ull c = red[tid * 16 + t2];
      if (c < k) k = c;
    }
    atomicMin(&best[m0 + tid], k);
  }
}

// ---------------- gather selected memory rows ----------------
__global__ __launch_bounds__(256) void gather_kernel(
    const float* __restrict__ bank, const ull* __restrict__ best,
    float* __restrict__ out) {
  const int b = blockIdx.x;
  const unsigned idx = (unsigned)(best[b] & 0xffffffffull);
  const float4* src = reinterpret_cast<const float4*>(bank + (size_t)idx * DD);
  float4* dst = reinterpret_cast<float4*>(out + (size_t)b * DD);
#pragma unroll
  for (int j = 0; j < 4; ++j)
    dst[threadIdx.x + 256 * j] = src[threadIdx.x + 256 * j];
}

// ---------------- conv layer 1: (1 or 3) -> 16, relu ----------------
__global__ __launch_bounds__(256) void conv_first_kernel(
    const float* __restrict__ p0, const float* __restrict__ p1,
    const float* __restrict__ p2, int ncin,
    const float* __restrict__ w, const float* __restrict__ bias,
    float* __restrict__ out) {
  __shared__ float sIn[3][18][18];
  __shared__ float sW[3][3][3][16];
  __shared__ float sB[16];
  const int tid = threadIdx.x;
  const int img = blockIdx.x >> 4;
  const int t = blockIdx.x & 15;
  const int y0 = (t >> 2) * 16, x0 = (t & 3) * 16;
  for (int i = tid; i < ncin * 144; i += 256) {
    int co = i & 15, r = i >> 4;
    int ci = r / 9, kk = r % 9;
    sW[ci][kk / 3][kk % 3][co] = w[(co * ncin + ci) * 9 + kk];
  }
  if (tid < 16) sB[tid] = bias[tid];
  const float* ps[3] = {p0, p1, p2};
  for (int i = tid; i < ncin * 18 * 18; i += 256) {
    int x = i % 18, rest = i / 18, yy = rest % 18, ci = rest / 18;
    int gx = x0 + x - 1, gy = y0 + yy - 1;
    float v = 0.f;
    if (gx >= 0 && gx < 64 && gy >= 0 && gy < 64)
      v = ps[ci][(size_t)img * DD + gy * 64 + gx];
    sIn[ci][yy][x] = v;
  }
  __syncthreads();
  const int ly = tid >> 4, lx = tid & 15;
  float acc[16];
#pragma unroll
  for (int co = 0; co < 16; ++co) acc[co] = sB[co];
  for (int ci = 0; ci < ncin; ++ci)
#pragma unroll
    for (int ky = 0; ky < 3; ++ky)
#pragma unroll
      for (int kx = 0; kx < 3; ++kx) {
        const float v = sIn[ci][ly + ky][lx + kx];
        const float4* wp = reinterpret_cast<const float4*>(&sW[ci][ky][kx][0]);
#pragma unroll
        for (int q = 0; q < 4; ++q) {
          float4 wq = wp[q];
          acc[q * 4 + 0] += wq.x * v; acc[q * 4 + 1] += wq.y * v;
          acc[q * 4 + 2] += wq.z * v; acc[q * 4 + 3] += wq.w * v;
        }
      }
  const int px = (y0 + ly) * 64 + (x0 + lx);
  float* ob = out + (size_t)img * HID * DD + px;
#pragma unroll
  for (int co = 0; co < 16; ++co) ob[co * DD] = fmaxf(acc[co], 0.f);
}

// ---------------- conv layer 2: 16 -> 16, relu ----------------
__global__ __launch_bounds__(256) void conv_mid_kernel(
    const float* __restrict__ in, const float* __restrict__ w,
    const float* __restrict__ bias, float* __restrict__ out) {
  __shared__ float sIn[16][18][34];
  __shared__ float sW[16][3][3][16];
  __shared__ float sB[16];
  const int tid = threadIdx.x;
  const int img = blockIdx.x >> 3;
  const int t = blockIdx.x & 7;
  const int y0 = (t >> 1) * 16, x0 = (t & 1) * 32;
  for (int i = tid; i < 2304; i += 256) {
    int co = i & 15, r = i >> 4;
    int ci = r / 9, kk = r % 9;
    sW[ci][kk / 3][kk % 3][co] = w[(co * 16 + ci) * 9 + kk];
  }
  if (tid < 16) sB[tid] = bias[tid];
  const float* ib = in + (size_t)img * HID * DD;
  for (int i = tid; i < 16 * 18 * 34; i += 256) {
    int x = i % 34, rest = i / 34, yy = rest % 18, ci = rest / 18;
    int gx = x0 + x - 1, gy = y0 + yy - 1;
    float v = 0.f;
    if (gx >= 0 && gx < 64 && gy >= 0 && gy < 64) v = ib[ci * DD + gy * 64 + gx];
    sIn[ci][yy][x] = v;
  }
  __syncthreads();
  const int ly = tid >> 4;
  const int lx = (tid & 15) * 2;
  float acc0[16], acc1[16];
#pragma unroll
  for (int co = 0; co < 16; ++co) { acc0[co] = sB[co]; acc1[co] = sB[co]; }
#pragma unroll 2
  for (int ci = 0; ci < 16; ++ci)
#pragma unroll
    for (int ky = 0; ky < 3; ++ky)
#pragma unroll
      for (int kx = 0; kx < 3; ++kx) {
        const float v0 = sIn[ci][ly + ky][lx + kx];
        const float v1 = sIn[ci][ly + ky][lx + kx + 1];
        const float4* wp = reinterpret_cast<const float4*>(&sW[ci][ky][kx][0]);
#pragma unroll
        for (int q = 0; q < 4; ++q) {
          float4 wq = wp[q];
          acc0[q * 4 + 0] += wq.x * v0; acc1[q * 4 + 0] += wq.x * v1;
          acc0[q * 4 + 1] += wq.y * v0; acc1[q * 4 + 1] += wq.y * v1;
          acc0[q * 4 + 2] += wq.z * v0; acc1[q * 4 + 2] += wq.z * v1;
          acc0[q * 4 + 3] += wq.w * v0; acc1[q * 4 + 3] += wq.w * v1;
        }
      }
  const int px = (y0 + ly) * 64 + (x0 + lx);
  float* ob = out + (size_t)img * HID * DD + px;
#pragma unroll
  for (int co = 0; co < 16; ++co) {
    ob[co * DD] = fmaxf(acc0[co], 0.f);
    ob[co * DD + 1] = fmaxf(acc1[co], 0.f);
  }
}

// ---------------- conv layer 3: 16 -> 1, +epilogue ----------------
__global__ __launch_bounds__(256) void conv_last_kernel(
    const float* __restrict__ in, const float* __restrict__ w,
    const float* __restrict__ bias, const float* __restrict__ addend,
    int mode, float* __restrict__ outp) {
  __shared__ float sIn[16][18][18];
  __shared__ float sW[16][9];
  const int tid = threadIdx.x;
  const int img = blockIdx.x >> 4;
  const int t = blockIdx.x & 15;
  const int y0 = (t >> 2) * 16, x0 = (t & 3) * 16;
  for (int i = tid; i < 144; i += 256) sW[i / 9][i % 9] = w[i];
  for (int i = tid; i < 16 * 18 * 18; i += 256) {
    int x = i % 18, rest = i / 18, yy = rest % 18, ci = rest / 18;
    int gx = x0 + x - 1, gy = y0 + yy - 1;
    float v = 0.f;
    if (gx >= 0 && gx < 64 && gy >= 0 && gy < 64)
      v = in[(size_t)img * HID * DD + ci * DD + gy * 64 + gx];
    sIn[ci][yy][x] = v;
  }
  __syncthreads();
  const int ly = tid >> 4, lx = tid & 15;
  float acc = bias[0];
#pragma unroll
  for (int ci = 0; ci < 16; ++ci)
#pragma unroll
    for (int ky = 0; ky < 3; ++ky)
#pragma unroll
      for (int kx = 0; kx < 3; ++kx)
        acc += sW[ci][ky * 3 + kx] * sIn[ci][ly + ky][lx + kx];
  const int px = (y0 + ly) * 64 + (x0 + lx);
  const float ad = addend[(size_t)img * DD + px];
  outp[(size_t)img * DD + px] = (mode == 0) ? (ad - acc) : (ad + acc);
}

extern "C" void kernel_launch(void* const* d_in, const int* in_sizes, int n_in,
                              void* d_out, int out_size, void* d_ws, size_t ws_size,
                              hipStream_t stream) {
  (void)in_sizes; (void)n_in; (void)out_size;
  const float* noisy = (const float*)d_in[0];
  const float* memN  = (const float*)d_in[1];
  const float* memC  = (const float*)d_in[2];
  const float* bw1 = (const float*)d_in[3];
  const float* bb1 = (const float*)d_in[4];
  const float* bw2 = (const float*)d_in[5];
  const float* bb2 = (const float*)d_in[6];
  const float* bw3 = (const float*)d_in[7];
  const float* bb3 = (const float*)d_in[8];
  const float* aw1 = (const float*)d_in[9];
  const float* ab1 = (const float*)d_in[10];
  const float* aw2 = (const float*)d_in[11];
  const float* ab2 = (const float*)d_in[12];
  const float* aw3 = (const float*)d_in[13];
  const float* ab3 = (const float*)d_in[14];
  float* out_f32 = (float*)d_out;

  char* ws = (char*)d_ws;
  size_t off = 0;
  auto take = [&](size_t bytes) -> char* {
    char* p = ws + off;
    off += (bytes + 255) & ~(size_t)255;
    return p;
  };
  float* b2 = (float*)take((size_t)NMEM * 4);
  float* a2 = (float*)take((size_t)B_IMG * 4);
  ull* best = (ull*)take((size_t)B_IMG * 8);
  float* base_out = (float*)take((size_t)B_IMG * DD * 4);
  float* mem_sel  = (float*)take((size_t)B_IMG * DD * 4);
  const size_t off_common = off;

  ushort* Bh = (ushort*)take((size_t)NMEM * DD * 2);
  ushort* Bl = (ushort*)take((size_t)NMEM * DD * 2);
  ushort* Ah = (ushort*)take((size_t)B_IMG * DD * 2);
  ushort* Al = (ushort*)take((size_t)B_IMG * DD * 2);
  const bool use_mfma = (off + 2ull * HID * DD * 4 + 1024) <= ws_size;
  if (!use_mfma) off = off_common;

  int CB = 128;
  while (CB > 1 && off + 2ull * CB * HID * DD * 4 + 512 > ws_size) CB >>= 1;
  float* h1 = (float*)take((size_t)CB * HID * DD * 4);
  float* h2 = (float*)take((size_t)CB * HID * DD * 4);

  hipMemsetAsync(best, 0xFF, (size_t)B_IMG * 8, stream);
  if (use_mfma) {
    split_kernel<<<NMEM, 256, 0, stream>>>(memN, Bh, Bl, b2);
    split_kernel<<<B_IMG, 256, 0, stream>>>(noisy, Ah, Al, a2);
    dist_mfma_kernel<<<(NMEM / 128) * (B_IMG / 128), 256, 0, stream>>>(
        Ah, Al, Bh, Bl, a2, b2, best);
  } else {
    sqnorm_kernel<<<NMEM, 256, 0, stream>>>(memN, b2);
    sqnorm_kernel<<<B_IMG, 256, 0, stream>>>(noisy, a2);
    dist_argmin_kernel<<<dim3(NMEM / 128, B_IMG / 128), 256, 0, stream>>>(
        noisy, memN, a2, b2, best);
  }
  gather_kernel<<<B_IMG, 256, 0, stream>>>(memC, best, mem_sel);

  for (int c0 = 0; c0 < B_IMG; c0 += CB) {
    const float* np_ = noisy + (size_t)c0 * DD;
    float* bo = base_out + (size_t)c0 * DD;
    const float* ms = mem_sel + (size_t)c0 * DD;
    conv_first_kernel<<<CB * 16, 256, 0, stream>>>(np_, nullptr, nullptr, 1, bw1, bb1, h1);
    conv_mid_kernel<<<CB * 8, 256, 0, stream>>>(h1, bw2, bb2, h2);
    conv_last_kernel<<<CB * 16, 256, 0, stream>>>(h2, bw3, bb3, np_, 0, bo);
    conv_first_kernel<<<CB * 16, 256, 0, stream>>>(np_, bo, ms, 3, aw1, ab1, h1);
    conv_mid_kernel<<<CB * 8, 256, 0, stream>>>(h1, aw2, ab2, h2);
    conv_last_kernel<<<CB * 16, 256, 0, stream>>>(
        h2, aw3, ab3, bo, 1, out_f32 + (size_t)c0 * DD);
  }
}

// Round 5
// 1285.364 us; speedup vs baseline: 2.5058x; 1.1682x over previous
//
#include <hip/hip_runtime.h>
#include <hip/hip_bf16.h>
#include <cstdint>

#define B_IMG 512
#define NMEM  32768
#define DD    4096
#define HID   16
#define OT    14   // fused conv output tile (14x14); h2=16x16, h1=18x18, in=20x20

typedef __attribute__((ext_vector_type(8))) short short8;
typedef __attribute__((ext_vector_type(4))) float f32x4;
typedef unsigned long long ull;

__device__ __forceinline__ void gload16(const void* g, const void* l) {
  __builtin_amdgcn_global_load_lds(
      (const __attribute__((address_space(1))) void*)g,
      (__attribute__((address_space(3))) void*)l, 16, 0, 0);
}

// ---------------- squared row norms (fallback path) ----------------
__global__ __launch_bounds__(256) void sqnorm_kernel(const float* __restrict__ x,
                                                     float* __restrict__ out) {
  const int row = blockIdx.x;
  const float4* p = reinterpret_cast<const float4*>(x + (size_t)row * DD);
  float s = 0.f;
#pragma unroll
  for (int j = 0; j < 4; ++j) {
    float4 v = p[threadIdx.x + 256 * j];
    s += v.x * v.x + v.y * v.y + v.z * v.z + v.w * v.w;
  }
#pragma unroll
  for (int o = 32; o > 0; o >>= 1) s += __shfl_down(s, o);
  __shared__ float ls[4];
  if ((threadIdx.x & 63) == 0) ls[threadIdx.x >> 6] = s;
  __syncthreads();
  if (threadIdx.x == 0) out[row] = (ls[0] + ls[1]) + (ls[2] + ls[3]);
}

// ---------------- split f32 -> bf16 hi/lo + row sqnorm ----------------
__global__ __launch_bounds__(256) void split_kernel(const float* __restrict__ x,
                                                    ushort* __restrict__ hi,
                                                    ushort* __restrict__ lo,
                                                    float* __restrict__ nrm) {
  const int row = blockIdx.x;
  const int t = threadIdx.x;
  const float4* p = reinterpret_cast<const float4*>(x + (size_t)row * DD);
  ushort4* ph = reinterpret_cast<ushort4*>(hi + (size_t)row * DD);
  ushort4* pl = reinterpret_cast<ushort4*>(lo + (size_t)row * DD);
  float s = 0.f;
#pragma unroll
  for (int j = 0; j < 4; ++j) {
    float4 v = p[t + 256 * j];
    float vv[4] = {v.x, v.y, v.z, v.w};
    ushort4 h, l;
    ushort* hp = &h.x;
    ushort* lp = &l.x;
#pragma unroll
    for (int q = 0; q < 4; ++q) {
      float f = vv[q];
      s += f * f;
      uint32_t u = __float_as_uint(f);
      uint32_t hb = (u + 0x7fffu + ((u >> 16) & 1u)) >> 16;  // RNE to bf16
      hp[q] = (ushort)hb;
      float fh = __uint_as_float(hb << 16);
      float fl = f - fh;  // exact
      uint32_t u2 = __float_as_uint(fl);
      lp[q] = (ushort)((u2 + 0x7fffu + ((u2 >> 16) & 1u)) >> 16);
    }
    ph[t + 256 * j] = h;
    pl[t + 256 * j] = l;
  }
#pragma unroll
  for (int o = 32; o > 0; o >>= 1) s += __shfl_down(s, o);
  __shared__ float ls[4];
  if ((t & 63) == 0) ls[t >> 6] = s;
  __syncthreads();
  if (t == 0) nrm[row] = (ls[0] + ls[1]) + (ls[2] + ls[3]);
}

// ---------------- split-bf16 MFMA distance GEMM + fused argmin ----------------
// acc = Ahi.Bhi + Ahi.Blo + Alo.Bhi ; dist = a2[m]+b2[n]-2*acc ; argmin per m.
__global__ __launch_bounds__(256) void dist_mfma_kernel(
    const ushort* __restrict__ Ah_g, const ushort* __restrict__ Al_g,
    const ushort* __restrict__ Bh_g, const ushort* __restrict__ Bl_g,
    const float* __restrict__ a2, const float* __restrict__ b2,
    ull* __restrict__ best) {
  const int d = blockIdx.x;
  const int xcd = d & 7;
  const int rest = d >> 3;
  const int mb = rest & 3;
  const int nb = (rest >> 2) * 8 + xcd;
  const int m0 = mb * 128;
  const int n0 = nb * 128;

  __shared__ short8 ldsbuf[2048];  // 32 KB: Ah | Al | Bh | Bl, each 128x32 bf16
  char* lb = (char*)ldsbuf;

  const int t = threadIdx.x;
  const int lane = t & 63;
  const int wid = t >> 6;
  const int wm = wid >> 1;
  const int wn = wid & 1;

  f32x4 acc[4][4];
#pragma unroll
  for (int mi = 0; mi < 4; ++mi)
#pragma unroll
    for (int ni = 0; ni < 4; ++ni) {
      f32x4 z = {0.f, 0.f, 0.f, 0.f};
      acc[mi][ni] = z;
    }

  const ushort* gptrs[4] = {Ah_g, Al_g, Bh_g, Bl_g};
  const int rbase[4] = {m0, m0, n0, n0};

  for (int k0 = 0; k0 < DD; k0 += 32) {
#pragma unroll
    for (int x = 0; x < 4; ++x) {
      const ushort* P = gptrs[x];
#pragma unroll
      for (int j = 0; j < 2; ++j) {
        const int e = (j * 256 + t) * 8;
        const int row = e >> 5;
        const int gpos = (e >> 3) & 3;
        const int col = ((gpos ^ ((row >> 1) & 3)) << 3);
        gload16(P + ((size_t)(rbase[x] + row) * DD + k0 + col),
                lb + x * 8192 + e * 2);
      }
    }
    __syncthreads();

    short8 ah[4], al[4];
#pragma unroll
    for (int mi = 0; mi < 4; ++mi) {
      const int r = wm * 64 + mi * 16 + (lane & 15);
      const int off = r * 64 + ((((lane >> 4) ^ (r >> 1)) & 3) << 4);
      ah[mi] = *(const short8*)(lb + off);
      al[mi] = *(const short8*)(lb + 8192 + off);
    }
#pragma unroll
    for (int ni = 0; ni < 4; ++ni) {
      const int r = wn * 64 + ni * 16 + (lane & 15);
      const int off = r * 64 + ((((lane >> 4) ^ (r >> 1)) & 3) << 4);
      short8 bh = *(const short8*)(lb + 16384 + off);
      short8 bl = *(const short8*)(lb + 24576 + off);
#pragma unroll
      for (int mi = 0; mi < 4; ++mi) {
        acc[mi][ni] = __builtin_amdgcn_mfma_f32_16x16x32_bf16(ah[mi], bh, acc[mi][ni], 0, 0, 0);
        acc[mi][ni] = __builtin_amdgcn_mfma_f32_16x16x32_bf16(ah[mi], bl, acc[mi][ni], 0, 0, 0);
        acc[mi][ni] = __builtin_amdgcn_mfma_f32_16x16x32_bf16(al[mi], bh, acc[mi][ni], 0, 0, 0);
      }
    }
    __syncthreads();
  }

#pragma unroll
  for (int mi = 0; mi < 4; ++mi)
#pragma unroll
    for (int j = 0; j < 4; ++j) {
      const int m = m0 + wm * 64 + mi * 16 + (lane >> 4) * 4 + j;
      const float a2v = a2[m];
      float bd = 3.4e38f;
      int bn = 0;
#pragma unroll
      for (int ni = 0; ni < 4; ++ni) {
        const int n = n0 + wn * 64 + ni * 16 + (lane & 15);
        const float dv = (a2v + b2[n]) - 2.0f * acc[mi][ni][j];
        if (dv < bd) { bd = dv; bn = n; }
      }
      ull key = ((ull)__float_as_uint(bd) << 32) | (unsigned)bn;
#pragma unroll
      for (int msk = 1; msk < 16; msk <<= 1) {
        ull o = __shfl_xor(key, msk);
        if (o < key) key = o;
      }
      if ((lane & 15) == 0) atomicMin(&best[m], key);
    }
}

// ---------------- fp32 fallback distance GEMM + argmin ----------------
__global__ __launch_bounds__(256) void dist_argmin_kernel(
    const float* __restrict__ A, const float* __restrict__ Bm,
    const float* __restrict__ a2, const float* __restrict__ b2,
    ull* __restrict__ best) {
  __shared__ float As[32][128];
  __shared__ float Bs[32][128];
  const int tid = threadIdx.x;
  const int m0 = blockIdx.y * 128;
  const int n0 = blockIdx.x * 128;
  const int tm = tid >> 4, tn = tid & 15;
  const int sr = tid >> 3;
  const int sc = (tid & 7) << 2;
  float acc[8][8];
#pragma unroll
  for (int i = 0; i < 8; ++i)
#pragma unroll
    for (int j = 0; j < 8; ++j) acc[i][j] = 0.f;
  for (int k0 = 0; k0 < DD; k0 += 32) {
    __syncthreads();
#pragma unroll
    for (int r = 0; r < 4; ++r) {
      const int row = sr + (r << 5);
      float4 va = *reinterpret_cast<const float4*>(&A[(size_t)(m0 + row) * DD + k0 + sc]);
      As[sc + 0][row] = va.x; As[sc + 1][row] = va.y;
      As[sc + 2][row] = va.z; As[sc + 3][row] = va.w;
      float4 vb = *reinterpret_cast<const float4*>(&Bm[(size_t)(n0 + row) * DD + k0 + sc]);
      Bs[sc + 0][row] = vb.x; Bs[sc + 1][row] = vb.y;
      Bs[sc + 2][row] = vb.z; Bs[sc + 3][row] = vb.w;
    }
    __syncthreads();
#pragma unroll 8
    for (int kk = 0; kk < 32; ++kk) {
      float4 a0 = *reinterpret_cast<const float4*>(&As[kk][tm * 8]);
      float4 a1 = *reinterpret_cast<const float4*>(&As[kk][tm * 8 + 4]);
      float4 b0 = *reinterpret_cast<const float4*>(&Bs[kk][tn * 8]);
      float4 b1 = *reinterpret_cast<const float4*>(&Bs[kk][tn * 8 + 4]);
      float a[8] = {a0.x, a0.y, a0.z, a0.w, a1.x, a1.y, a1.z, a1.w};
      float b[8] = {b0.x, b0.y, b0.z, b0.w, b1.x, b1.y, b1.z, b1.w};
#pragma unroll
      for (int i = 0; i < 8; ++i)
#pragma unroll
        for (int j = 0; j < 8; ++j) acc[i][j] += a[i] * b[j];
    }
  }
  __syncthreads();
  ull* red = reinterpret_cast<ull*>(&As[0][0]);
#pragma unroll
  for (int i = 0; i < 8; ++i) {
    const int m = m0 + tm * 8 + i;
    const float a2v = a2[m];
    float bd = 3.4e38f;
    int bn = 0;
#pragma unroll
    for (int j = 0; j < 8; ++j) {
      const int n = n0 + tn * 8 + j;
      const float dval = (a2v + b2[n]) - 2.0f * acc[i][j];
      if (dval < bd) { bd = dval; bn = n; }
    }
    red[(tm * 8 + i) * 16 + tn] = ((ull)__float_as_uint(bd) << 32) | (unsigned)bn;
  }
  __syncthreads();
  if (tid < 128) {
    ull k = red[tid * 16];
#pragma unroll
    for (int t2 = 1; t2 < 16; ++t2) {
      ull c = red[tid * 16 + t2];
      if (c < k) k = c;
    }
    atomicMin(&best[m0 + tid], k);
  }
}

// ---------------- weight transpose: [co][ci][3][3] -> [(ci*9+kk)][co] ----------------
__global__ __launch_bounds__(256) void wtrans_kernel(const float* __restrict__ w,
                                                     int ncin, float* __restrict__ wt) {
  const int i = blockIdx.x * 256 + threadIdx.x;
  if (i < ncin * 144) {
    const int co = i & 15, r = i >> 4;  // r = ci*9+kk
    const int ci = r / 9, kk = r % 9;
    wt[(ci * 9 + kk) * 16 + co] = w[(co * ncin + ci) * 9 + kk];
  }
}

// ---------------- fused 3-layer conv pipeline on a 14x14 output tile ----------------
// out = addend + sign * conv3(relu(conv2(relu(conv1(channels)))))
// SAME padding per layer: intermediates are ZERO outside the 64x64 image.
template <int NCIN>
__global__ __launch_bounds__(256) void fused_conv3_kernel(
    const float* __restrict__ chan0, const float* __restrict__ chan1,
    const float* __restrict__ memC, const ull* __restrict__ best,
    const float* __restrict__ wt1, const float* __restrict__ b1v,
    const float* __restrict__ wt2, const float* __restrict__ b2v,
    const float* __restrict__ w3, const float* __restrict__ b3v,
    const float* __restrict__ addend, float sign, float* __restrict__ outp) {
  __shared__ float sIn[NCIN * 400];      // [ci][20][20], halo 3
  __shared__ float sH1[16][18][18];
  __shared__ float sH2[16][16][16];
  const int tid = threadIdx.x;
  const int img = blockIdx.x / 25;
  const int t = blockIdx.x % 25;
  const int y0 = (t / 5) * OT, x0 = (t % 5) * OT;

  const float* cptr[NCIN];
  cptr[0] = chan0 + (size_t)img * DD;
  if (NCIN == 3) {
    cptr[1] = chan1 + (size_t)img * DD;
    cptr[2] = memC + (size_t)(unsigned)(best[img] & 0xffffffffull) * DD;
  }

  // stage input 20x20 per channel (global offset -3)
  for (int i = tid; i < NCIN * 400; i += 256) {
    const int ci = i / 400, r = i % 400, yy = r / 20, xx = r % 20;
    const int gy = y0 + yy - 3, gx = x0 + xx - 3;
    float v = 0.f;
    if (gy >= 0 && gy < 64 && gx >= 0 && gx < 64) v = cptr[ci][gy * 64 + gx];
    sIn[ci * 400 + yy * 20 + xx] = v;
  }
  __syncthreads();

  // L1 -> h1 on 18x18 (h1[y][x] ~ global (y0+y-2, x0+x-2)); zero outside image
  for (int p = tid; p < 324; p += 256) {
    const int y = p / 18, x = p % 18;
    const int gy = y0 + y - 2, gx = x0 + x - 2;
    const bool inimg = (gy >= 0 && gy < 64 && gx >= 0 && gx < 64);
    float acc[16];
#pragma unroll
    for (int co = 0; co < 16; ++co) acc[co] = b1v[co];
#pragma unroll
    for (int ci = 0; ci < NCIN; ++ci)
#pragma unroll
      for (int kk = 0; kk < 9; ++kk) {
        const float v = sIn[ci * 400 + (y + kk / 3) * 20 + (x + kk % 3)];
        const float4* wq = reinterpret_cast<const float4*>(wt1 + (ci * 9 + kk) * 16);
#pragma unroll
        for (int q = 0; q < 4; ++q) {
          float4 w = wq[q];
          acc[4 * q + 0] += w.x * v; acc[4 * q + 1] += w.y * v;
          acc[4 * q + 2] += w.z * v; acc[4 * q + 3] += w.w * v;
        }
      }
#pragma unroll
    for (int co = 0; co < 16; ++co)
      sH1[co][y][x] = inimg ? fmaxf(acc[co], 0.f) : 0.f;
  }
  __syncthreads();

  // L2 -> h2 on 16x16 (h2[y][x] ~ global (y0+y-1, x0+x-1)); zero outside image
  {
    const int y = tid >> 4, x = tid & 15;
    const int gy = y0 + y - 1, gx = x0 + x - 1;
    const bool inimg = (gy >= 0 && gy < 64 && gx >= 0 && gx < 64);
    float acc[16];
#pragma unroll
    for (int co = 0; co < 16; ++co) acc[co] = b2v[co];
#pragma unroll 4
    for (int ci = 0; ci < 16; ++ci)
#pragma unroll
      for (int kk = 0; kk < 9; ++kk) {
        const float v = sH1[ci][y + kk / 3][x + kk % 3];
        const float4* wq = reinterpret_cast<const float4*>(wt2 + (ci * 9 + kk) * 16);
#pragma unroll
        for (int q = 0; q < 4; ++q) {
          float4 w = wq[q];
          acc[4 * q + 0] += w.x * v; acc[4 * q + 1] += w.y * v;
          acc[4 * q + 2] += w.z * v; acc[4 * q + 3] += w.w * v;
        }
      }
#pragma unroll
    for (int co = 0; co < 16; ++co)
      sH2[co][y][x] = inimg ? fmaxf(acc[co], 0.f) : 0.f;
  }
  __syncthreads();

  // L3 + epilogue on 14x14
  if (tid < OT * OT) {
    const int y = tid / OT, x = tid % OT;
    const int gy = y0 + y, gx = x0 + x;
    if (gy < 64 && gx < 64) {
      float acc = b3v[0];
#pragma unroll 4
      for (int ci = 0; ci < 16; ++ci)
#pragma unroll
        for (int kk = 0; kk < 9; ++kk)
          acc += w3[ci * 9 + kk] * sH2[ci][y + kk / 3][x + kk % 3];
      const size_t o = (size_t)img * DD + gy * 64 + gx;
      outp[o] = addend[o] + sign * acc;
    }
  }
}

extern "C" void kernel_launch(void* const* d_in, const int* in_sizes, int n_in,
                              void* d_out, int out_size, void* d_ws, size_t ws_size,
                              hipStream_t stream) {
  (void)in_sizes; (void)n_in; (void)out_size;
  const float* noisy = (const float*)d_in[0];
  const float* memN  = (const float*)d_in[1];
  const float* memC  = (const float*)d_in[2];
  const float* bw1 = (const float*)d_in[3];
  const float* bb1 = (const float*)d_in[4];
  const float* bw2 = (const float*)d_in[5];
  const float* bb2 = (const float*)d_in[6];
  const float* bw3 = (const float*)d_in[7];
  const float* bb3 = (const float*)d_in[8];
  const float* aw1 = (const float*)d_in[9];
  const float* ab1 = (const float*)d_in[10];
  const float* aw2 = (const float*)d_in[11];
  const float* ab2 = (const float*)d_in[12];
  const float* aw3 = (const float*)d_in[13];
  const float* ab3 = (const float*)d_in[14];
  float* out_f32 = (float*)d_out;

  char* ws = (char*)d_ws;
  size_t off = 0;
  auto take = [&](size_t bytes) -> char* {
    char* p = ws + off;
    off += (bytes + 255) & ~(size_t)255;
    return p;
  };
  float* b2 = (float*)take((size_t)NMEM * 4);
  float* a2 = (float*)take((size_t)B_IMG * 4);
  ull* best = (ull*)take((size_t)B_IMG * 8);
  float* base_out = (float*)take((size_t)B_IMG * DD * 4);
  float* wtb1 = (float*)take(144 * 4);
  float* wtb2 = (float*)take(2304 * 4);
  float* wta1 = (float*)take(432 * 4);
  float* wta2 = (float*)take(2304 * 4);
  const size_t off_common = off;

  ushort* Bh = (ushort*)take((size_t)NMEM * DD * 2);
  ushort* Bl = (ushort*)take((size_t)NMEM * DD * 2);
  ushort* Ah = (ushort*)take((size_t)B_IMG * DD * 2);
  ushort* Al = (ushort*)take((size_t)B_IMG * DD * 2);
  const bool use_mfma = (off + 1024) <= ws_size;
  if (!use_mfma) off = off_common;

  // weight transposes (tiny)
  wtrans_kernel<<<1, 256, 0, stream>>>(bw1, 1, wtb1);
  wtrans_kernel<<<9, 256, 0, stream>>>(bw2, 16, wtb2);
  wtrans_kernel<<<2, 256, 0, stream>>>(aw1, 3, wta1);
  wtrans_kernel<<<9, 256, 0, stream>>>(aw2, 16, wta2);

  hipMemsetAsync(best, 0xFF, (size_t)B_IMG * 8, stream);
  if (use_mfma) {
    split_kernel<<<NMEM, 256, 0, stream>>>(memN, Bh, Bl, b2);
    split_kernel<<<B_IMG, 256, 0, stream>>>(noisy, Ah, Al, a2);
    dist_mfma_kernel<<<(NMEM / 128) * (B_IMG / 128), 256, 0, stream>>>(
        Ah, Al, Bh, Bl, a2, b2, best);
  } else {
    sqnorm_kernel<<<NMEM, 256, 0, stream>>>(memN, b2);
    sqnorm_kernel<<<B_IMG, 256, 0, stream>>>(noisy, a2);
    dist_argmin_kernel<<<dim3(NMEM / 128, B_IMG / 128), 256, 0, stream>>>(
        noisy, memN, a2, b2, best);
  }

  // base denoiser: base_out = noisy - conv3(relu(conv2(relu(conv1(noisy)))))
  fused_conv3_kernel<1><<<B_IMG * 25, 256, 0, stream>>>(
      noisy, nullptr, nullptr, nullptr,
      wtb1, bb1, wtb2, bb2, bw3, bb3, noisy, -1.0f, base_out);
  // adapter: out = base_out + conv3(relu(conv2(relu(conv1([noisy, base_out, memC[best]])))))
  fused_conv3_kernel<3><<<B_IMG * 25, 256, 0, stream>>>(
      noisy, base_out, memC, best,
      wta1, ab1, wta2, ab2, aw3, ab3, base_out, 1.0f, out_f32);
}

// Round 6
// 1158.417 us; speedup vs baseline: 2.7804x; 1.1096x over previous
//
#include <hip/hip_runtime.h>
#include <hip/hip_bf16.h>
#include <cstdint>

#define B_IMG 512
#define NMEM  32768
#define DD    4096
#define HID   16

typedef __attribute__((ext_vector_type(8))) short short8;
typedef __attribute__((ext_vector_type(4))) float f32x4;
typedef unsigned long long ull;

__device__ __forceinline__ void gload16(const void* g, const void* l) {
  __builtin_amdgcn_global_load_lds(
      (const __attribute__((address_space(1))) void*)g,
      (__attribute__((address_space(3))) void*)l, 16, 0, 0);
}

__device__ __forceinline__ ushort to_bf16u(float f) {
  uint32_t u = __float_as_uint(f);
  return (ushort)((u + 0x7fffu + ((u >> 16) & 1u)) >> 16);
}

// ---------------- squared row norms (fallback path) ----------------
__global__ __launch_bounds__(256) void sqnorm_kernel(const float* __restrict__ x,
                                                     float* __restrict__ out) {
  const int row = blockIdx.x;
  const float4* p = reinterpret_cast<const float4*>(x + (size_t)row * DD);
  float s = 0.f;
#pragma unroll
  for (int j = 0; j < 4; ++j) {
    float4 v = p[threadIdx.x + 256 * j];
    s += v.x * v.x + v.y * v.y + v.z * v.z + v.w * v.w;
  }
#pragma unroll
  for (int o = 32; o > 0; o >>= 1) s += __shfl_down(s, o);
  __shared__ float ls[4];
  if ((threadIdx.x & 63) == 0) ls[threadIdx.x >> 6] = s;
  __syncthreads();
  if (threadIdx.x == 0) out[row] = (ls[0] + ls[1]) + (ls[2] + ls[3]);
}

// ---------------- split f32 -> bf16 hi/lo + row sqnorm ----------------
__global__ __launch_bounds__(256) void split_kernel(const float* __restrict__ x,
                                                    ushort* __restrict__ hi,
                                                    ushort* __restrict__ lo,
                                                    float* __restrict__ nrm) {
  const int row = blockIdx.x;
  const int t = threadIdx.x;
  const float4* p = reinterpret_cast<const float4*>(x + (size_t)row * DD);
  ushort4* ph = reinterpret_cast<ushort4*>(hi + (size_t)row * DD);
  ushort4* pl = reinterpret_cast<ushort4*>(lo + (size_t)row * DD);
  float s = 0.f;
#pragma unroll
  for (int j = 0; j < 4; ++j) {
    float4 v = p[t + 256 * j];
    float vv[4] = {v.x, v.y, v.z, v.w};
    ushort4 h, l;
    ushort* hp = &h.x;
    ushort* lp = &l.x;
#pragma unroll
    for (int q = 0; q < 4; ++q) {
      float f = vv[q];
      s += f * f;
      uint32_t u = __float_as_uint(f);
      uint32_t hb = (u + 0x7fffu + ((u >> 16) & 1u)) >> 16;  // RNE to bf16
      hp[q] = (ushort)hb;
      float fh = __uint_as_float(hb << 16);
      float fl = f - fh;  // exact
      uint32_t u2 = __float_as_uint(fl);
      lp[q] = (ushort)((u2 + 0x7fffu + ((u2 >> 16) & 1u)) >> 16);
    }
    ph[t + 256 * j] = h;
    pl[t + 256 * j] = l;
  }
#pragma unroll
  for (int o = 32; o > 0; o >>= 1) s += __shfl_down(s, o);
  __shared__ float ls[4];
  if ((t & 63) == 0) ls[t >> 6] = s;
  __syncthreads();
  if (t == 0) nrm[row] = (ls[0] + ls[1]) + (ls[2] + ls[3]);
}

// ---------------- split-bf16 MFMA distance GEMM + fused argmin ----------------
__global__ __launch_bounds__(256) void dist_mfma_kernel(
    const ushort* __restrict__ Ah_g, const ushort* __restrict__ Al_g,
    const ushort* __restrict__ Bh_g, const ushort* __restrict__ Bl_g,
    const float* __restrict__ a2, const float* __restrict__ b2,
    ull* __restrict__ best) {
  const int d = blockIdx.x;
  const int xcd = d & 7;
  const int rest = d >> 3;
  const int mb = rest & 3;
  const int nb = (rest >> 2) * 8 + xcd;
  const int m0 = mb * 128;
  const int n0 = nb * 128;

  __shared__ short8 ldsbuf[2048];  // 32 KB: Ah | Al | Bh | Bl, each 128x32 bf16
  char* lb = (char*)ldsbuf;

  const int t = threadIdx.x;
  const int lane = t & 63;
  const int wid = t >> 6;
  const int wm = wid >> 1;
  const int wn = wid & 1;

  f32x4 acc[4][4];
#pragma unroll
  for (int mi = 0; mi < 4; ++mi)
#pragma unroll
    for (int ni = 0; ni < 4; ++ni) {
      f32x4 z = {0.f, 0.f, 0.f, 0.f};
      acc[mi][ni] = z;
    }

  const ushort* gptrs[4] = {Ah_g, Al_g, Bh_g, Bl_g};
  const int rbase[4] = {m0, m0, n0, n0};

  for (int k0 = 0; k0 < DD; k0 += 32) {
#pragma unroll
    for (int x = 0; x < 4; ++x) {
      const ushort* P = gptrs[x];
#pragma unroll
      for (int j = 0; j < 2; ++j) {
        const int e = (j * 256 + t) * 8;
        const int row = e >> 5;
        const int gpos = (e >> 3) & 3;
        const int col = ((gpos ^ ((row >> 1) & 3)) << 3);
        gload16(P + ((size_t)(rbase[x] + row) * DD + k0 + col),
                lb + x * 8192 + e * 2);
      }
    }
    __syncthreads();

    short8 ah[4], al[4];
#pragma unroll
    for (int mi = 0; mi < 4; ++mi) {
      const int r = wm * 64 + mi * 16 + (lane & 15);
      const int off = r * 64 + ((((lane >> 4) ^ (r >> 1)) & 3) << 4);
      ah[mi] = *(const short8*)(lb + off);
      al[mi] = *(const short8*)(lb + 8192 + off);
    }
#pragma unroll
    for (int ni = 0; ni < 4; ++ni) {
      const int r = wn * 64 + ni * 16 + (lane & 15);
      const int off = r * 64 + ((((lane >> 4) ^ (r >> 1)) & 3) << 4);
      short8 bh = *(const short8*)(lb + 16384 + off);
      short8 bl = *(const short8*)(lb + 24576 + off);
#pragma unroll
      for (int mi = 0; mi < 4; ++mi) {
        acc[mi][ni] = __builtin_amdgcn_mfma_f32_16x16x32_bf16(ah[mi], bh, acc[mi][ni], 0, 0, 0);
        acc[mi][ni] = __builtin_amdgcn_mfma_f32_16x16x32_bf16(ah[mi], bl, acc[mi][ni], 0, 0, 0);
        acc[mi][ni] = __builtin_amdgcn_mfma_f32_16x16x32_bf16(al[mi], bh, acc[mi][ni], 0, 0, 0);
      }
    }
    __syncthreads();
  }

#pragma unroll
  for (int mi = 0; mi < 4; ++mi)
#pragma unroll
    for (int j = 0; j < 4; ++j) {
      const int m = m0 + wm * 64 + mi * 16 + (lane >> 4) * 4 + j;
      const float a2v = a2[m];
      float bd = 3.4e38f;
      int bn = 0;
#pragma unroll
      for (int ni = 0; ni < 4; ++ni) {
        const int n = n0 + wn * 64 + ni * 16 + (lane & 15);
        const float dv = (a2v + b2[n]) - 2.0f * acc[mi][ni][j];
        if (dv < bd) { bd = dv; bn = n; }
      }
      ull key = ((ull)__float_as_uint(bd) << 32) | (unsigned)bn;
#pragma unroll
      for (int msk = 1; msk < 16; msk <<= 1) {
        ull o = __shfl_xor(key, msk);
        if (o < key) key = o;
      }
      if ((lane & 15) == 0) atomicMin(&best[m], key);
    }
}

// ---------------- fp32 fallback distance GEMM + argmin ----------------
__global__ __launch_bounds__(256) void dist_argmin_kernel(
    const float* __restrict__ A, const float* __restrict__ Bm,
    const float* __restrict__ a2, const float* __restrict__ b2,
    ull* __restrict__ best) {
  __shared__ float As[32][128];
  __shared__ float Bs[32][128];
  const int tid = threadIdx.x;
  const int m0 = blockIdx.y * 128;
  const int n0 = blockIdx.x * 128;
  const int tm = tid >> 4, tn = tid & 15;
  const int sr = tid >> 3;
  const int sc = (tid & 7) << 2;
  float acc[8][8];
#pragma unroll
  for (int i = 0; i < 8; ++i)
#pragma unroll
    for (int j = 0; j < 8; ++j) acc[i][j] = 0.f;
  for (int k0 = 0; k0 < DD; k0 += 32) {
    __syncthreads();
#pragma unroll
    for (int r = 0; r < 4; ++r) {
      const int row = sr + (r << 5);
      float4 va = *reinterpret_cast<const float4*>(&A[(size_t)(m0 + row) * DD + k0 + sc]);
      As[sc + 0][row] = va.x; As[sc + 1][row] = va.y;
      As[sc + 2][row] = va.z; As[sc + 3][row] = va.w;
      float4 vb = *reinterpret_cast<const float4*>(&Bm[(size_t)(n0 + row) * DD + k0 + sc]);
      Bs[sc + 0][row] = vb.x; Bs[sc + 1][row] = vb.y;
      Bs[sc + 2][row] = vb.z; Bs[sc + 3][row] = vb.w;
    }
    __syncthreads();
#pragma unroll 8
    for (int kk = 0; kk < 32; ++kk) {
      float4 a0 = *reinterpret_cast<const float4*>(&As[kk][tm * 8]);
      float4 a1 = *reinterpret_cast<const float4*>(&As[kk][tm * 8 + 4]);
      float4 b0 = *reinterpret_cast<const float4*>(&Bs[kk][tn * 8]);
      float4 b1 = *reinterpret_cast<const float4*>(&Bs[kk][tn * 8 + 4]);
      float a[8] = {a0.x, a0.y, a0.z, a0.w, a1.x, a1.y, a1.z, a1.w};
      float b[8] = {b0.x, b0.y, b0.z, b0.w, b1.x, b1.y, b1.z, b1.w};
#pragma unroll
      for (int i = 0; i < 8; ++i)
#pragma unroll
        for (int j = 0; j < 8; ++j) acc[i][j] += a[i] * b[j];
    }
  }
  __syncthreads();
  ull* red = reinterpret_cast<ull*>(&As[0][0]);
#pragma unroll
  for (int i = 0; i < 8; ++i) {
    const int m = m0 + tm * 8 + i;
    const float a2v = a2[m];
    float bd = 3.4e38f;
    int bn = 0;
#pragma unroll
    for (int j = 0; j < 8; ++j) {
      const int n = n0 + tn * 8 + j;
      const float dval = (a2v + b2[n]) - 2.0f * acc[i][j];
      if (dval < bd) { bd = dval; bn = n; }
    }
    red[(tm * 8 + i) * 16 + tn] = ((ull)__float_as_uint(bd) << 32) | (unsigned)bn;
  }
  __syncthreads();
  if (tid < 128) {
    ull k = red[tid * 16];
#pragma unroll
    for (int t2 = 1; t2 < 16; ++t2) {
      ull c = red[tid * 16 + t2];
      if (c < k) k = c;
    }
    atomicMin(&best[m0 + tid], k);
  }
}

// ---------------- weight prep per pipeline ----------------
// wt1: [(ci*9+kk)][co] f32 (for VALU L1)
// wh2/wl2: [co][160] bf16 hi/lo, k = tap*16+ci (k>=144 -> 0)
// wh3/wl3: [16][160] bf16 hi/lo, row 0 = w3, rows 1-15 = 0
__global__ __launch_bounds__(256) void wprep_kernel(
    const float* __restrict__ w1, const float* __restrict__ w2,
    const float* __restrict__ w3, int ncin,
    float* __restrict__ wt1, ushort* __restrict__ wh2, ushort* __restrict__ wl2,
    ushort* __restrict__ wh3, ushort* __restrict__ wl3) {
  const int i = blockIdx.x * 256 + threadIdx.x;
  const int n1 = ncin * 144;
  if (i < n1) {
    const int co = i & 15, r = i >> 4;
    const int ci = r / 9, kk = r % 9;
    wt1[(ci * 9 + kk) * 16 + co] = w1[(co * ncin + ci) * 9 + kk];
  } else if (i < n1 + 5120) {
    const int j = i - n1;
    const int which = j / 2560;        // 0 -> L2, 1 -> L3
    const int jj = j % 2560;
    const int co = jj / 160, k = jj % 160;
    float f = 0.f;
    if (which == 0) {
      if (k < 144) f = w2[co * 144 + (k & 15) * 9 + (k >> 4)];
    } else {
      if (co == 0 && k < 144) f = w3[(k & 15) * 9 + (k >> 4)];
    }
    const ushort hb = to_bf16u(f);
    const float fl = f - __uint_as_float((uint32_t)hb << 16);
    ushort* dh = (which == 0) ? wh2 : wh3;
    ushort* dl = (which == 0) ? wl2 : wl3;
    dh[co * 160 + k] = hb;
    dl[co * 160 + k] = to_bf16u(fl);
  }
}

// ---------------- fused 3-layer conv: L1 VALU, L2+L3 MFMA ----------------
// out = addend + sign * conv3(relu(conv2(relu(conv1(channels)))))
// SAME padding per layer (intermediates zero outside the 64x64 image).
// h1/h2 stored in LDS as 2 bf16 planes [18][18][8ci] (16B per pixel per plane).
template <int NCIN>
__global__ __launch_bounds__(256) void fused_conv3_kernel(
    const float* __restrict__ chan0, const float* __restrict__ chan1,
    const float* __restrict__ memC, const ull* __restrict__ best,
    const float* __restrict__ wt1, const float* __restrict__ b1v,
    const ushort* __restrict__ wh2, const ushort* __restrict__ wl2,
    const float* __restrict__ b2v,
    const ushort* __restrict__ wh3, const ushort* __restrict__ wl3,
    const float* __restrict__ b3v,
    const float* __restrict__ addend, float sign, float* __restrict__ outp) {
  constexpr int SIN_SZ = NCIN * 1600;      // [ci][20][20] f32
  constexpr int H1 = SIN_SZ;               // 2 planes x 5184 B
  constexpr int H2 = H1 + 10368;           // 2 planes x 5184 B
  constexpr int ZP = H2 + 10368;           // 64 B zeros
  __shared__ __align__(16) char smem[SIN_SZ + 20736 + 64];
  float* sIn = (float*)smem;

  const int tid = threadIdx.x;
  const int lane = tid & 63, wid = tid >> 6;
  const int img = blockIdx.x / 25;
  const int t = blockIdx.x % 25;
  const int y0 = (t / 5) * 14, x0 = (t % 5) * 14;

  const float* cptr[NCIN];
  cptr[0] = chan0 + (size_t)img * DD;
  if (NCIN == 3) {
    cptr[1] = chan1 + (size_t)img * DD;
    cptr[2] = memC + (size_t)(unsigned)(best[img] & 0xffffffffull) * DD;
  }

  if (tid < 16) *(float*)(smem + ZP + tid * 4) = 0.f;
  // stage input 20x20 per channel (global offset -3)
  for (int i = tid; i < NCIN * 400; i += 256) {
    const int ci = i / 400, r = i % 400, yy = r / 20, xx = r % 20;
    const int gy = y0 + yy - 3, gx = x0 + xx - 3;
    float v = 0.f;
    if (gy >= 0 && gy < 64 && gx >= 0 && gx < 64) v = cptr[ci][gy * 64 + gx];
    sIn[ci * 400 + yy * 20 + xx] = v;
  }
  __syncthreads();

  // ---- L1 (VALU) -> h1 bf16 planes on 18x18; zero outside image ----
  for (int p = tid; p < 324; p += 256) {
    const int y = p / 18, x = p % 18;
    const int gy = y0 + y - 2, gx = x0 + x - 2;
    const bool inimg = (gy >= 0 && gy < 64 && gx >= 0 && gx < 64);
    float acc[16];
#pragma unroll
    for (int co = 0; co < 16; ++co) acc[co] = b1v[co];
#pragma unroll
    for (int ci = 0; ci < NCIN; ++ci)
#pragma unroll
      for (int kk = 0; kk < 9; ++kk) {
        const float v = sIn[ci * 400 + (y + kk / 3) * 20 + (x + kk % 3)];
        const float4* wq = reinterpret_cast<const float4*>(wt1 + (ci * 9 + kk) * 16);
#pragma unroll
        for (int q = 0; q < 4; ++q) {
          float4 w = wq[q];
          acc[4 * q + 0] += w.x * v; acc[4 * q + 1] += w.y * v;
          acc[4 * q + 2] += w.z * v; acc[4 * q + 3] += w.w * v;
        }
      }
    short8 h0, h1v;
#pragma unroll
    for (int c = 0; c < 8; ++c) {
      h0[c] = (short)(inimg ? to_bf16u(fmaxf(acc[c], 0.f)) : 0);
      h1v[c] = (short)(inimg ? to_bf16u(fmaxf(acc[8 + c], 0.f)) : 0);
    }
    *(short8*)(smem + H1 + (y * 18 + x) * 16) = h0;
    *(short8*)(smem + H1 + 5184 + (y * 18 + x) * 16) = h1v;
  }
  __syncthreads();

  // ---- L2 (MFMA) -> h2 bf16 planes on 16x16 grid; zero outside image ----
  const int xn = lane & 15;   // px x  (B col) == co row for A
  const int xk = lane >> 4;   // k-granule
  f32x4 acc2[4];
#pragma unroll
  for (int g = 0; g < 4; ++g) { f32x4 z = {0.f, 0.f, 0.f, 0.f}; acc2[g] = z; }
#pragma unroll
  for (int kq = 0; kq < 5; ++kq) {
    const int k0 = kq * 32;
    const int we = xn * 160 + k0 + xk * 8;
    short8 ah = *(const short8*)(wh2 + we);
    short8 al = *(const short8*)(wl2 + we);
    const int kb = k0 + xk * 8;
    const int tap = kb >> 4, cih = (kb >> 3) & 1;
    const bool zp = (tap >= 9);
    const int dy = tap / 3, dx = tap % 3;
    const int bbase = H1 + cih * 5184 + ((dy * 18) + xn + dx) * 16;
#pragma unroll
    for (int g = 0; g < 4; ++g) {
      const int y = wid * 4 + g;
      const int boff = zp ? ZP : (bbase + y * 288);
      short8 b = *(const short8*)(smem + boff);
      acc2[g] = __builtin_amdgcn_mfma_f32_16x16x32_bf16(ah, b, acc2[g], 0, 0, 0);
      acc2[g] = __builtin_amdgcn_mfma_f32_16x16x32_bf16(al, b, acc2[g], 0, 0, 0);
    }
  }
#pragma unroll
  for (int g = 0; g < 4; ++g) {
    const int y = wid * 4 + g;
    const int gy = y0 + y - 1, gx = x0 + xn - 1;
    const bool inimg = (gy >= 0 && gy < 64 && gx >= 0 && gx < 64);
#pragma unroll
    for (int j = 0; j < 4; ++j) {
      const int co = xk * 4 + j;
      const float v = inimg ? fmaxf(acc2[g][j] + b2v[co], 0.f) : 0.f;
      *(ushort*)(smem + H2 + (co >> 3) * 5184 + (y * 18 + xn) * 16 + (co & 7) * 2) =
          to_bf16u(v);
    }
  }
  __syncthreads();

  // ---- L3 (MFMA, only D-row co=0 used) + epilogue on 14x14 ----
  f32x4 acc3[4];
#pragma unroll
  for (int g = 0; g < 4; ++g) { f32x4 z = {0.f, 0.f, 0.f, 0.f}; acc3[g] = z; }
#pragma unroll
  for (int kq = 0; kq < 5; ++kq) {
    const int k0 = kq * 32;
    const int we = xn * 160 + k0 + xk * 8;
    short8 ah = *(const short8*)(wh3 + we);
    short8 al = *(const short8*)(wl3 + we);
    const int kb = k0 + xk * 8;
    const int tap = kb >> 4, cih = (kb >> 3) & 1;
    const bool zp = (tap >= 9);
    const int dy = tap / 3, dx = tap % 3;
    const int bbase = H2 + cih * 5184 + ((dy * 18) + xn + dx) * 16;
#pragma unroll
    for (int g = 0; g < 4; ++g) {
      const int y = wid * 4 + g;
      const int boff = zp ? ZP : (bbase + y * 288);
      short8 b = *(const short8*)(smem + boff);
      acc3[g] = __builtin_amdgcn_mfma_f32_16x16x32_bf16(ah, b, acc3[g], 0, 0, 0);
      acc3[g] = __builtin_amdgcn_mfma_f32_16x16x32_bf16(al, b, acc3[g], 0, 0, 0);
    }
  }
  if (xk == 0) {
#pragma unroll
    for (int g = 0; g < 4; ++g) {
      const int y = wid * 4 + g;
      const int gy = y0 + y, gx = x0 + xn;
      if (y < 14 && xn < 14 && gy < 64 && gx < 64) {
        const size_t o = (size_t)img * DD + gy * 64 + gx;
        outp[o] = addend[o] + sign * (acc3[g][0] + b3v[0]);
      }
    }
  }
}

extern "C" void kernel_launch(void* const* d_in, const int* in_sizes, int n_in,
                              void* d_out, int out_size, void* d_ws, size_t ws_size,
                              hipStream_t stream) {
  (void)in_sizes; (void)n_in; (void)out_size;
  const float* noisy = (const float*)d_in[0];
  const float* memN  = (const float*)d_in[1];
  const float* memC  = (const float*)d_in[2];
  const float* bw1 = (const float*)d_in[3];
  const float* bb1 = (const float*)d_in[4];
  const float* bw2 = (const float*)d_in[5];
  const float* bb2 = (const float*)d_in[6];
  const float* bw3 = (const float*)d_in[7];
  const float* bb3 = (const float*)d_in[8];
  const float* aw1 = (const float*)d_in[9];
  const float* ab1 = (const float*)d_in[10];
  const float* aw2 = (const float*)d_in[11];
  const float* ab2 = (const float*)d_in[12];
  const float* aw3 = (const float*)d_in[13];
  const float* ab3 = (const float*)d_in[14];
  float* out_f32 = (float*)d_out;

  char* ws = (char*)d_ws;
  size_t off = 0;
  auto take = [&](size_t bytes) -> char* {
    char* p = ws + off;
    off += (bytes + 255) & ~(size_t)255;
    return p;
  };
  float* b2 = (float*)take((size_t)NMEM * 4);
  float* a2 = (float*)take((size_t)B_IMG * 4);
  ull* best = (ull*)take((size_t)B_IMG * 8);
  float* base_out = (float*)take((size_t)B_IMG * DD * 4);
  // per-pipeline weight tables
  float* wt1b = (float*)take(144 * 4);
  ushort* wh2b = (ushort*)take(2560 * 2);
  ushort* wl2b = (ushort*)take(2560 * 2);
  ushort* wh3b = (ushort*)take(2560 * 2);
  ushort* wl3b = (ushort*)take(2560 * 2);
  float* wt1a = (float*)take(432 * 4);
  ushort* wh2a = (ushort*)take(2560 * 2);
  ushort* wl2a = (ushort*)take(2560 * 2);
  ushort* wh3a = (ushort*)take(2560 * 2);
  ushort* wl3a = (ushort*)take(2560 * 2);
  const size_t off_common = off;

  ushort* Bh = (ushort*)take((size_t)NMEM * DD * 2);
  ushort* Bl = (ushort*)take((size_t)NMEM * DD * 2);
  ushort* Ah = (ushort*)take((size_t)B_IMG * DD * 2);
  ushort* Al = (ushort*)take((size_t)B_IMG * DD * 2);
  const bool use_mfma = (off + 1024) <= ws_size;
  if (!use_mfma) off = off_common;

  // weight prep (tiny)
  wprep_kernel<<<21, 256, 0, stream>>>(bw1, bw2, bw3, 1, wt1b, wh2b, wl2b, wh3b, wl3b);
  wprep_kernel<<<22, 256, 0, stream>>>(aw1, aw2, aw3, 3, wt1a, wh2a, wl2a, wh3a, wl3a);

  hipMemsetAsync(best, 0xFF, (size_t)B_IMG * 8, stream);
  if (use_mfma) {
    split_kernel<<<NMEM, 256, 0, stream>>>(memN, Bh, Bl, b2);
    split_kernel<<<B_IMG, 256, 0, stream>>>(noisy, Ah, Al, a2);
    dist_mfma_kernel<<<(NMEM / 128) * (B_IMG / 128), 256, 0, stream>>>(
        Ah, Al, Bh, Bl, a2, b2, best);
  } else {
    sqnorm_kernel<<<NMEM, 256, 0, stream>>>(memN, b2);
    sqnorm_kernel<<<B_IMG, 256, 0, stream>>>(noisy, a2);
    dist_argmin_kernel<<<dim3(NMEM / 128, B_IMG / 128), 256, 0, stream>>>(
        noisy, memN, a2, b2, best);
  }

  // base denoiser: base_out = noisy - conv3(relu(conv2(relu(conv1(noisy)))))
  fused_conv3_kernel<1><<<B_IMG * 25, 256, 0, stream>>>(
      noisy, nullptr, nullptr, nullptr,
      wt1b, bb1, wh2b, wl2b, bb2, wh3b, wl3b, bb3, noisy, -1.0f, base_out);
  // adapter: out = base_out + conv3(relu(conv2(relu(conv1([noisy, base_out, memC[best]])))))
  fused_conv3_kernel<3><<<B_IMG * 25, 256, 0, stream>>>(
      noisy, base_out, memC, best,
      wt1a, ab1, wh2a, wl2a, ab2, wh3a, wl3a, ab3, base_out, 1.0f, out_f32);
}

// Round 7
// 941.805 us; speedup vs baseline: 3.4199x; 1.2300x over previous
//
#include <hip/hip_runtime.h>
#include <hip/hip_bf16.h>
#include <cstdint>

#define B_IMG 512
#define NMEM  32768
#define DD    4096
#define HID   16

typedef __attribute__((ext_vector_type(8))) short short8;
typedef __attribute__((ext_vector_type(4))) float f32x4;
typedef unsigned long long ull;

__device__ __forceinline__ void gload16(const void* g, const void* l) {
  __builtin_amdgcn_global_load_lds(
      (const __attribute__((address_space(1))) void*)g,
      (__attribute__((address_space(3))) void*)l, 16, 0, 0);
}

__device__ __forceinline__ ushort to_bf16u(float f) {
  uint32_t u = __float_as_uint(f);
  return (ushort)((u + 0x7fffu + ((u >> 16) & 1u)) >> 16);
}

// ---------------- squared row norms (fallback path) ----------------
__global__ __launch_bounds__(256) void sqnorm_kernel(const float* __restrict__ x,
                                                     float* __restrict__ out) {
  const int row = blockIdx.x;
  const float4* p = reinterpret_cast<const float4*>(x + (size_t)row * DD);
  float s = 0.f;
#pragma unroll
  for (int j = 0; j < 4; ++j) {
    float4 v = p[threadIdx.x + 256 * j];
    s += v.x * v.x + v.y * v.y + v.z * v.z + v.w * v.w;
  }
#pragma unroll
  for (int o = 32; o > 0; o >>= 1) s += __shfl_down(s, o);
  __shared__ float ls[4];
  if ((threadIdx.x & 63) == 0) ls[threadIdx.x >> 6] = s;
  __syncthreads();
  if (threadIdx.x == 0) out[row] = (ls[0] + ls[1]) + (ls[2] + ls[3]);
}

// ---------------- split f32 -> bf16 hi + row sqnorm ----------------
__global__ __launch_bounds__(256) void split_hi_kernel(const float* __restrict__ x,
                                                       ushort* __restrict__ hi,
                                                       float* __restrict__ nrm) {
  const int row = blockIdx.x;
  const int t = threadIdx.x;
  const float4* p = reinterpret_cast<const float4*>(x + (size_t)row * DD);
  ushort4* ph = reinterpret_cast<ushort4*>(hi + (size_t)row * DD);
  float s = 0.f;
#pragma unroll
  for (int j = 0; j < 4; ++j) {
    float4 v = p[t + 256 * j];
    float vv[4] = {v.x, v.y, v.z, v.w};
    ushort4 h;
    ushort* hp = &h.x;
#pragma unroll
    for (int q = 0; q < 4; ++q) {
      float f = vv[q];
      s += f * f;
      hp[q] = to_bf16u(f);
    }
    ph[t + 256 * j] = h;
  }
#pragma unroll
  for (int o = 32; o > 0; o >>= 1) s += __shfl_down(s, o);
  __shared__ float ls[4];
  if ((t & 63) == 0) ls[t >> 6] = s;
  __syncthreads();
  if (t == 0) nrm[row] = (ls[0] + ls[1]) + (ls[2] + ls[3]);
}

// ---------------- pass 1: 1-term bf16 MFMA distance GEMM -> approx dists ----------------
__global__ __launch_bounds__(256) void dist1_kernel(
    const ushort* __restrict__ Ah_g, const ushort* __restrict__ Bh_g,
    const float* __restrict__ a2, const float* __restrict__ b2,
    float* __restrict__ dists) {
  const int d = blockIdx.x;
  const int xcd = d & 7;
  const int rest = d >> 3;
  const int mb = rest & 3;
  const int nb = (rest >> 2) * 8 + xcd;
  const int m0 = mb * 128;
  const int n0 = nb * 128;

  __shared__ short8 ldsbuf[1024];  // 16 KB: Ah | Bh, each 128x32 bf16
  char* lb = (char*)ldsbuf;

  const int t = threadIdx.x;
  const int lane = t & 63;
  const int wid = t >> 6;
  const int wm = wid >> 1;
  const int wn = wid & 1;

  f32x4 acc[4][4];
#pragma unroll
  for (int mi = 0; mi < 4; ++mi)
#pragma unroll
    for (int ni = 0; ni < 4; ++ni) {
      f32x4 z = {0.f, 0.f, 0.f, 0.f};
      acc[mi][ni] = z;
    }

  const ushort* gptrs[2] = {Ah_g, Bh_g};
  const int rbase[2] = {m0, n0};

  for (int k0 = 0; k0 < DD; k0 += 32) {
#pragma unroll
    for (int x = 0; x < 2; ++x) {
      const ushort* P = gptrs[x];
#pragma unroll
      for (int j = 0; j < 2; ++j) {
        const int e = (j * 256 + t) * 8;
        const int row = e >> 5;
        const int gpos = (e >> 3) & 3;
        const int col = ((gpos ^ ((row >> 1) & 3)) << 3);
        gload16(P + ((size_t)(rbase[x] + row) * DD + k0 + col),
                lb + x * 8192 + e * 2);
      }
    }
    __syncthreads();

    short8 ah[4];
#pragma unroll
    for (int mi = 0; mi < 4; ++mi) {
      const int r = wm * 64 + mi * 16 + (lane & 15);
      const int off = r * 64 + ((((lane >> 4) ^ (r >> 1)) & 3) << 4);
      ah[mi] = *(const short8*)(lb + off);
    }
#pragma unroll
    for (int ni = 0; ni < 4; ++ni) {
      const int r = wn * 64 + ni * 16 + (lane & 15);
      const int off = r * 64 + ((((lane >> 4) ^ (r >> 1)) & 3) << 4);
      short8 bh = *(const short8*)(lb + 8192 + off);
#pragma unroll
      for (int mi = 0; mi < 4; ++mi)
        acc[mi][ni] = __builtin_amdgcn_mfma_f32_16x16x32_bf16(ah[mi], bh, acc[mi][ni], 0, 0, 0);
    }
    __syncthreads();
  }

  // epilogue: approx dist -> global
#pragma unroll
  for (int mi = 0; mi < 4; ++mi)
#pragma unroll
    for (int j = 0; j < 4; ++j) {
      const int m = m0 + wm * 64 + mi * 16 + (lane >> 4) * 4 + j;
      const float a2v = a2[m];
#pragma unroll
      for (int ni = 0; ni < 4; ++ni) {
        const int n = n0 + wn * 64 + ni * 16 + (lane & 15);
        dists[(size_t)m * NMEM + n] = (a2v + b2[n]) - 2.0f * acc[mi][ni][j];
      }
    }
}

// ---------------- pass 2: per-row approx-min -> candidates -> exact refine ----------------
#define MARGIN 4.0f
#define MAXC 128
__global__ __launch_bounds__(256) void refine_kernel(
    const float* __restrict__ dists, const float* __restrict__ A,
    const float* __restrict__ Bm, const float* __restrict__ a2,
    const float* __restrict__ b2, ull* __restrict__ best) {
  const int m = blockIdx.x;
  const int t = threadIdx.x;
  const int lane = t & 63, wid = t >> 6;
  const float4* r4 = reinterpret_cast<const float4*>(dists + (size_t)m * NMEM);

  // phase A: approx min value
  float lmin = 3.4e38f;
  for (int i = t; i < NMEM / 4; i += 256) {
    float4 v = r4[i];
    lmin = fminf(lmin, fminf(fminf(v.x, v.y), fminf(v.z, v.w)));
  }
#pragma unroll
  for (int o = 32; o > 0; o >>= 1) lmin = fminf(lmin, __shfl_down(lmin, o));
  __shared__ float ws4[4];
  __shared__ float red[4];
  __shared__ int cnt;
  __shared__ int cand[MAXC];
  if (lane == 0) ws4[wid] = lmin;
  if (t == 0) cnt = 0;
  __syncthreads();
  const float thresh = fminf(fminf(ws4[0], ws4[1]), fminf(ws4[2], ws4[3])) + MARGIN;

  // phase B: collect candidates
  for (int i = t; i < NMEM / 4; i += 256) {
    float4 v = r4[i];
    float vv[4] = {v.x, v.y, v.z, v.w};
#pragma unroll
    for (int q = 0; q < 4; ++q)
      if (vv[q] < thresh) {
        int c = atomicAdd(&cnt, 1);
        if (c < MAXC) cand[c] = i * 4 + q;
      }
  }
  __syncthreads();
  const int nc = min(cnt, MAXC);

  // phase C: exact fp32 distance for each candidate; keep min key
  ull bkey = ~0ull;
  const float4* a4 = reinterpret_cast<const float4*>(A + (size_t)m * DD);
  for (int c = 0; c < nc; ++c) {
    const int n = cand[c];
    const float4* b4 = reinterpret_cast<const float4*>(Bm + (size_t)n * DD);
    float s = 0.f;
    for (int i = t; i < DD / 4; i += 256) {
      float4 av = a4[i], bv = b4[i];
      s += av.x * bv.x + av.y * bv.y + av.z * bv.z + av.w * bv.w;
    }
#pragma unroll
    for (int o = 32; o > 0; o >>= 1) s += __shfl_down(s, o);
    if (lane == 0) red[wid] = s;
    __syncthreads();
    if (t == 0) {
      const float dot = (red[0] + red[1]) + (red[2] + red[3]);
      const float dv = (a2[m] + b2[n]) - 2.0f * dot;
      const ull key = ((ull)__float_as_uint(dv) << 32) | (unsigned)n;
      if (key < bkey) bkey = key;
    }
    __syncthreads();
  }
  if (t == 0) best[m] = bkey;
}

// ---------------- fp32 fallback distance GEMM + argmin ----------------
__global__ __launch_bounds__(256) void dist_argmin_kernel(
    const float* __restrict__ A, const float* __restrict__ Bm,
    const float* __restrict__ a2, const float* __restrict__ b2,
    ull* __restrict__ best) {
  __shared__ float As[32][128];
  __shared__ float Bs[32][128];
  const int tid = threadIdx.x;
  const int m0 = blockIdx.y * 128;
  const int n0 = blockIdx.x * 128;
  const int tm = tid >> 4, tn = tid & 15;
  const int sr = tid >> 3;
  const int sc = (tid & 7) << 2;
  float acc[8][8];
#pragma unroll
  for (int i = 0; i < 8; ++i)
#pragma unroll
    for (int j = 0; j < 8; ++j) acc[i][j] = 0.f;
  for (int k0 = 0; k0 < DD; k0 += 32) {
    __syncthreads();
#pragma unroll
    for (int r = 0; r < 4; ++r) {
      const int row = sr + (r << 5);
      float4 va = *reinterpret_cast<const float4*>(&A[(size_t)(m0 + row) * DD + k0 + sc]);
      As[sc + 0][row] = va.x; As[sc + 1][row] = va.y;
      As[sc + 2][row] = va.z; As[sc + 3][row] = va.w;
      float4 vb = *reinterpret_cast<const float4*>(&Bm[(size_t)(n0 + row) * DD + k0 + sc]);
      Bs[sc + 0][row] = vb.x; Bs[sc + 1][row] = vb.y;
      Bs[sc + 2][row] = vb.z; Bs[sc + 3][row] = vb.w;
    }
    __syncthreads();
#pragma unroll 8
    for (int kk = 0; kk < 32; ++kk) {
      float4 a0 = *reinterpret_cast<const float4*>(&As[kk][tm * 8]);
      float4 a1 = *reinterpret_cast<const float4*>(&As[kk][tm * 8 + 4]);
      float4 b0 = *reinterpret_cast<const float4*>(&Bs[kk][tn * 8]);
      float4 b1 = *reinterpret_cast<const float4*>(&Bs[kk][tn * 8 + 4]);
      float a[8] = {a0.x, a0.y, a0.z, a0.w, a1.x, a1.y, a1.z, a1.w};
      float b[8] = {b0.x, b0.y, b0.z, b0.w, b1.x, b1.y, b1.z, b1.w};
#pragma unroll
      for (int i = 0; i < 8; ++i)
#pragma unroll
        for (int j = 0; j < 8; ++j) acc[i][j] += a[i] * b[j];
    }
  }
  __syncthreads();
  ull* red = reinterpret_cast<ull*>(&As[0][0]);
#pragma unroll
  for (int i = 0; i < 8; ++i) {
    const int m = m0 + tm * 8 + i;
    const float a2v = a2[m];
    float bd = 3.4e38f;
    int bn = 0;
#pragma unroll
    for (int j = 0; j < 8; ++j) {
      const int n = n0 + tn * 8 + j;
      const float dval = (a2v + b2[n]) - 2.0f * acc[i][j];
      if (dval < bd) { bd = dval; bn = n; }
    }
    red[(tm * 8 + i) * 16 + tn] = ((ull)__float_as_uint(bd) << 32) | (unsigned)bn;
  }
  __syncthreads();
  if (tid < 128) {
    ull k = red[tid * 16];
#pragma unroll
    for (int t2 = 1; t2 < 16; ++t2) {
      ull c = red[tid * 16 + t2];
      if (c < k) k = c;
    }
    atomicMin(&best[m0 + tid], k);
  }
}

// ---------------- weight prep per pipeline ----------------
__global__ __launch_bounds__(256) void wprep_kernel(
    const float* __restrict__ w1, const float* __restrict__ w2,
    const float* __restrict__ w3, int ncin,
    float* __restrict__ wt1, ushort* __restrict__ wh2, ushort* __restrict__ wl2,
    ushort* __restrict__ wh3, ushort* __restrict__ wl3) {
  const int i = blockIdx.x * 256 + threadIdx.x;
  const int n1 = ncin * 144;
  if (i < n1) {
    const int co = i & 15, r = i >> 4;
    const int ci = r / 9, kk = r % 9;
    wt1[(ci * 9 + kk) * 16 + co] = w1[(co * ncin + ci) * 9 + kk];
  } else if (i < n1 + 5120) {
    const int j = i - n1;
    const int which = j / 2560;        // 0 -> L2, 1 -> L3
    const int jj = j % 2560;
    const int co = jj / 160, k = jj % 160;
    float f = 0.f;
    if (which == 0) {
      if (k < 144) f = w2[co * 144 + (k & 15) * 9 + (k >> 4)];
    } else {
      if (co == 0 && k < 144) f = w3[(k & 15) * 9 + (k >> 4)];
    }
    const ushort hb = to_bf16u(f);
    const float fl = f - __uint_as_float((uint32_t)hb << 16);
    ushort* dh = (which == 0) ? wh2 : wh3;
    ushort* dl = (which == 0) ? wl2 : wl3;
    dh[co * 160 + k] = hb;
    dl[co * 160 + k] = to_bf16u(fl);
  }
}

// ---------------- fused 3-layer conv: L1 VALU, L2+L3 MFMA ----------------
template <int NCIN>
__global__ __launch_bounds__(256) void fused_conv3_kernel(
    const float* __restrict__ chan0, const float* __restrict__ chan1,
    const float* __restrict__ memC, const ull* __restrict__ best,
    const float* __restrict__ wt1, const float* __restrict__ b1v,
    const ushort* __restrict__ wh2, const ushort* __restrict__ wl2,
    const float* __restrict__ b2v,
    const ushort* __restrict__ wh3, const ushort* __restrict__ wl3,
    const float* __restrict__ b3v,
    const float* __restrict__ addend, float sign, float* __restrict__ outp) {
  constexpr int SIN_SZ = NCIN * 1600;      // [ci][20][20] f32
  constexpr int H1 = SIN_SZ;               // 2 planes x 5184 B
  constexpr int H2 = H1 + 10368;           // 2 planes x 5184 B
  constexpr int ZP = H2 + 10368;           // 64 B zeros
  __shared__ __align__(16) char smem[SIN_SZ + 20736 + 64];
  float* sIn = (float*)smem;

  const int tid = threadIdx.x;
  const int lane = tid & 63, wid = tid >> 6;
  const int img = blockIdx.x / 25;
  const int t = blockIdx.x % 25;
  const int y0 = (t / 5) * 14, x0 = (t % 5) * 14;

  const float* cptr[NCIN];
  cptr[0] = chan0 + (size_t)img * DD;
  if (NCIN == 3) {
    cptr[1] = chan1 + (size_t)img * DD;
    cptr[2] = memC + (size_t)(unsigned)(best[img] & 0xffffffffull) * DD;
  }

  if (tid < 16) *(float*)(smem + ZP + tid * 4) = 0.f;
  for (int i = tid; i < NCIN * 400; i += 256) {
    const int ci = i / 400, r = i % 400, yy = r / 20, xx = r % 20;
    const int gy = y0 + yy - 3, gx = x0 + xx - 3;
    float v = 0.f;
    if (gy >= 0 && gy < 64 && gx >= 0 && gx < 64) v = cptr[ci][gy * 64 + gx];
    sIn[ci * 400 + yy * 20 + xx] = v;
  }
  __syncthreads();

  // ---- L1 (VALU) -> h1 bf16 planes on 18x18; zero outside image ----
  for (int p = tid; p < 324; p += 256) {
    const int y = p / 18, x = p % 18;
    const int gy = y0 + y - 2, gx = x0 + x - 2;
    const bool inimg = (gy >= 0 && gy < 64 && gx >= 0 && gx < 64);
    float acc[16];
#pragma unroll
    for (int co = 0; co < 16; ++co) acc[co] = b1v[co];
#pragma unroll
    for (int ci = 0; ci < NCIN; ++ci)
#pragma unroll
      for (int kk = 0; kk < 9; ++kk) {
        const float v = sIn[ci * 400 + (y + kk / 3) * 20 + (x + kk % 3)];
        const float4* wq = reinterpret_cast<const float4*>(wt1 + (ci * 9 + kk) * 16);
#pragma unroll
        for (int q = 0; q < 4; ++q) {
          float4 w = wq[q];
          acc[4 * q + 0] += w.x * v; acc[4 * q + 1] += w.y * v;
          acc[4 * q + 2] += w.z * v; acc[4 * q + 3] += w.w * v;
        }
      }
    short8 h0, h1v;
#pragma unroll
    for (int c = 0; c < 8; ++c) {
      h0[c] = (short)(inimg ? to_bf16u(fmaxf(acc[c], 0.f)) : 0);
      h1v[c] = (short)(inimg ? to_bf16u(fmaxf(acc[8 + c], 0.f)) : 0);
    }
    *(short8*)(smem + H1 + (y * 18 + x) * 16) = h0;
    *(short8*)(smem + H1 + 5184 + (y * 18 + x) * 16) = h1v;
  }
  __syncthreads();

  // ---- L2 (MFMA) -> h2 bf16 planes on 16x16 grid; zero outside image ----
  const int xn = lane & 15;
  const int xk = lane >> 4;
  f32x4 acc2[4];
#pragma unroll
  for (int g = 0; g < 4; ++g) { f32x4 z = {0.f, 0.f, 0.f, 0.f}; acc2[g] = z; }
#pragma unroll
  for (int kq = 0; kq < 5; ++kq) {
    const int k0 = kq * 32;
    const int we = xn * 160 + k0 + xk * 8;
    short8 ah = *(const short8*)(wh2 + we);
    short8 al = *(const short8*)(wl2 + we);
    const int kb = k0 + xk * 8;
    const int tap = kb >> 4, cih = (kb >> 3) & 1;
    const bool zp = (tap >= 9);
    const int dy = tap / 3, dx = tap % 3;
    const int bbase = H1 + cih * 5184 + ((dy * 18) + xn + dx) * 16;
#pragma unroll
    for (int g = 0; g < 4; ++g) {
      const int y = wid * 4 + g;
      const int boff = zp ? ZP : (bbase + y * 288);
      short8 b = *(const short8*)(smem + boff);
      acc2[g] = __builtin_amdgcn_mfma_f32_16x16x32_bf16(ah, b, acc2[g], 0, 0, 0);
      acc2[g] = __builtin_amdgcn_mfma_f32_16x16x32_bf16(al, b, acc2[g], 0, 0, 0);
    }
  }
#pragma unroll
  for (int g = 0; g < 4; ++g) {
    const int y = wid * 4 + g;
    const int gy = y0 + y - 1, gx = x0 + xn - 1;
    const bool inimg = (gy >= 0 && gy < 64 && gx >= 0 && gx < 64);
#pragma unroll
    for (int j = 0; j < 4; ++j) {
      const int co = xk * 4 + j;
      const float v = inimg ? fmaxf(acc2[g][j] + b2v[co], 0.f) : 0.f;
      *(ushort*)(smem + H2 + (co >> 3) * 5184 + (y * 18 + xn) * 16 + (co & 7) * 2) =
          to_bf16u(v);
    }
  }
  __syncthreads();

  // ---- L3 (MFMA, only D-row co=0 used) + epilogue on 14x14 ----
  f32x4 acc3[4];
#pragma unroll
  for (int g = 0; g < 4; ++g) { f32x4 z = {0.f, 0.f, 0.f, 0.f}; acc3[g] = z; }
#pragma unroll
  for (int kq = 0; kq < 5; ++kq) {
    const int k0 = kq * 32;
    const int we = xn * 160 + k0 + xk * 8;
    short8 ah = *(const short8*)(wh3 + we);
    short8 al = *(const short8*)(wl3 + we);
    const int kb = k0 + xk * 8;
    const int tap = kb >> 4, cih = (kb >> 3) & 1;
    const bool zp = (tap >= 9);
    const int dy = tap / 3, dx = tap % 3;
    const int bbase = H2 + cih * 5184 + ((dy * 18) + xn + dx) * 16;
#pragma unroll
    for (int g = 0; g < 4; ++g) {
      const int y = wid * 4 + g;
      const int boff = zp ? ZP : (bbase + y * 288);
      short8 b = *(const short8*)(smem + boff);
      acc3[g] = __builtin_amdgcn_mfma_f32_16x16x32_bf16(ah, b, acc3[g], 0, 0, 0);
      acc3[g] = __builtin_amdgcn_mfma_f32_16x16x32_bf16(al, b, acc3[g], 0, 0, 0);
    }
  }
  if (xk == 0) {
#pragma unroll
    for (int g = 0; g < 4; ++g) {
      const int y = wid * 4 + g;
      const int gy = y0 + y, gx = x0 + xn;
      if (y < 14 && xn < 14 && gy < 64 && gx < 64) {
        const size_t o = (size_t)img * DD + gy * 64 + gx;
        outp[o] = addend[o] + sign * (acc3[g][0] + b3v[0]);
      }
    }
  }
}

extern "C" void kernel_launch(void* const* d_in, const int* in_sizes, int n_in,
                              void* d_out, int out_size, void* d_ws, size_t ws_size,
                              hipStream_t stream) {
  (void)in_sizes; (void)n_in; (void)out_size;
  const float* noisy = (const float*)d_in[0];
  const float* memN  = (const float*)d_in[1];
  const float* memC  = (const float*)d_in[2];
  const float* bw1 = (const float*)d_in[3];
  const float* bb1 = (const float*)d_in[4];
  const float* bw2 = (const float*)d_in[5];
  const float* bb2 = (const float*)d_in[6];
  const float* bw3 = (const float*)d_in[7];
  const float* bb3 = (const float*)d_in[8];
  const float* aw1 = (const float*)d_in[9];
  const float* ab1 = (const float*)d_in[10];
  const float* aw2 = (const float*)d_in[11];
  const float* ab2 = (const float*)d_in[12];
  const float* aw3 = (const float*)d_in[13];
  const float* ab3 = (const float*)d_in[14];
  float* out_f32 = (float*)d_out;

  char* ws = (char*)d_ws;
  size_t off = 0;
  auto take = [&](size_t bytes) -> char* {
    char* p = ws + off;
    off += (bytes + 255) & ~(size_t)255;
    return p;
  };
  float* b2 = (float*)take((size_t)NMEM * 4);
  float* a2 = (float*)take((size_t)B_IMG * 4);
  ull* best = (ull*)take((size_t)B_IMG * 8);
  float* base_out = (float*)take((size_t)B_IMG * DD * 4);
  float* wt1b = (float*)take(144 * 4);
  ushort* wh2b = (ushort*)take(2560 * 2);
  ushort* wl2b = (ushort*)take(2560 * 2);
  ushort* wh3b = (ushort*)take(2560 * 2);
  ushort* wl3b = (ushort*)take(2560 * 2);
  float* wt1a = (float*)take(432 * 4);
  ushort* wh2a = (ushort*)take(2560 * 2);
  ushort* wl2a = (ushort*)take(2560 * 2);
  ushort* wh3a = (ushort*)take(2560 * 2);
  ushort* wl3a = (ushort*)take(2560 * 2);
  const size_t off_common = off;

  ushort* Bh = (ushort*)take((size_t)NMEM * DD * 2);
  ushort* Ah = (ushort*)take((size_t)B_IMG * DD * 2);
  float* dists = (float*)take((size_t)B_IMG * NMEM * 4);
  const bool use_mfma = (off + 1024) <= ws_size;
  if (!use_mfma) off = off_common;

  // weight prep (tiny)
  wprep_kernel<<<21, 256, 0, stream>>>(bw1, bw2, bw3, 1, wt1b, wh2b, wl2b, wh3b, wl3b);
  wprep_kernel<<<22, 256, 0, stream>>>(aw1, aw2, aw3, 3, wt1a, wh2a, wl2a, wh3a, wl3a);

  hipMemsetAsync(best, 0xFF, (size_t)B_IMG * 8, stream);
  if (use_mfma) {
    split_hi_kernel<<<NMEM, 256, 0, stream>>>(memN, Bh, b2);
    split_hi_kernel<<<B_IMG, 256, 0, stream>>>(noisy, Ah, a2);
    dist1_kernel<<<(NMEM / 128) * (B_IMG / 128), 256, 0, stream>>>(
        Ah, Bh, a2, b2, dists);
    refine_kernel<<<B_IMG, 256, 0, stream>>>(dists, noisy, memN, a2, b2, best);
  } else {
    sqnorm_kernel<<<NMEM, 256, 0, stream>>>(memN, b2);
    sqnorm_kernel<<<B_IMG, 256, 0, stream>>>(noisy, a2);
    dist_argmin_kernel<<<dim3(NMEM / 128, B_IMG / 128), 256, 0, stream>>>(
        noisy, memN, a2, b2, best);
  }

  // base denoiser: base_out = noisy - conv3(relu(conv2(relu(conv1(noisy)))))
  fused_conv3_kernel<1><<<B_IMG * 25, 256, 0, stream>>>(
      noisy, nullptr, nullptr, nullptr,
      wt1b, bb1, wh2b, wl2b, bb2, wh3b, wl3b, bb3, noisy, -1.0f, base_out);
  // adapter: out = base_out + conv3(relu(conv2(relu(conv1([noisy, base_out, memC[best]])))))
  fused_conv3_kernel<3><<<B_IMG * 25, 256, 0, stream>>>(
      noisy, base_out, memC, best,
      wt1a, ab1, wh2a, wl2a, ab2, wh3a, wl3a, ab3, base_out, 1.0f, out_f32);
}